// Round 12
// baseline (348.626 us; speedup 1.0000x reference)
//
#include <hip/hip_runtime.h>
#include <hip/hip_bf16.h>
#include <hip/hip_fp16.h>

#define NUSERS 100000
#define NITEMS 50000
#define NN     150001          // total nodes
#define NNZ    3200000         // 2 * NNZ_INTER
#define BATCH  4096
#define DIM    64
#define ND     (NN * DIM)
#define ALPHA  0.25f           // 1/(N_LAYERS+1)
#define INVT   5.0f            // 1/TEMP
#define LAMBDA 0.1f
#define REGC   1.0e-4f
#define BKSH   9               // 512 nodes per bucket
#define NB     293             // ceil(150001/512)
#define ACHUNK 4096            // edges per bucketA block
#define M0     5.0f            // fixed LSE shift: logits = sim/T ∈ [-5,5]
#define NGB    256             // k_gather blocks (BATCH*16/256)
#define BHB    256             // k_bhist blocks
#define CMASK  0x3FFFF         // 18-bit col mask
#define SPMVB  2048            // k_spmv grid (8 blocks/CU -> 32 waves/CU)
#define W8SCALE 1024.f         // fp8 storage scale for w0
#define LGAIN   4.f            // per-layer gain (keeps fp8 values in sweet range)

typedef __attribute__((ext_vector_type(8))) short v8s;    // 8 bf16 (4 VGPRs)
typedef __attribute__((ext_vector_type(4))) float f32x4;  // MFMA acc
typedef __attribute__((ext_vector_type(2))) float f32x2;  // packed f32 pair

__device__ __forceinline__ float wred64(float v) {
  for (int o = 32; o > 0; o >>= 1) v += __shfl_xor(v, o);
  return v;
}

__device__ __forceinline__ float softplusf(float x) {
  return (x > 20.f) ? x : log1pf(__expf(x));
}

__device__ __forceinline__ unsigned short bf16r(float v) {
  unsigned x = __float_as_uint(v);
  return (unsigned short)((x + 0x7fff + ((x >> 16) & 1)) >> 16);   // RNE
}

// fp8 quad (uint = 4 x e4m3) -> float4 (HW cvt)
__device__ __forceinline__ float4 q8f(unsigned W) {
  f32x2 lo = __builtin_amdgcn_cvt_pk_f32_fp8(W, false);
  f32x2 hi = __builtin_amdgcn_cvt_pk_f32_fp8(W, true);
  return make_float4(lo.x, lo.y, hi.x, hi.y);
}

// float4 -> fp8 quad
__device__ __forceinline__ unsigned f4q8(float a, float b, float c, float d) {
  int w = __builtin_amdgcn_cvt_pk_fp8_f32(a, b, 0, false);
  w = __builtin_amdgcn_cvt_pk_fp8_f32(c, d, w, true);
  return (unsigned)w;
}

// ---------------- zero scratch + preset LSE state + invperm ----------------
__global__ void k_zero(int* __restrict__ bhist, float* __restrict__ S,
                       float* __restrict__ m_u, float* __restrict__ s_u,
                       float* __restrict__ m_p, float* __restrict__ s_p,
                       const int* __restrict__ perm, int* __restrict__ inv) {
  int i = blockIdx.x * blockDim.x + threadIdx.x;
  if (i < NB) bhist[i] = 0;
  if (i < 256) S[i] = 0.f;
  if (i < BATCH) {
    s_u[i] = 0.f; s_p[i] = 0.f; m_u[i] = M0; m_p[i] = M0;
    inv[perm[i]] = i;
  }
}

// ---------------- s0 = W8SCALE * rsqrt(deg) * x0, fp8 quads ----------------
__global__ void k_inith(const float4* __restrict__ uemb, const float4* __restrict__ iemb,
                        const float* __restrict__ rsq, unsigned* __restrict__ x0q) {
  int q = blockIdx.x * blockDim.x + threadIdx.x;   // quads: NN*16
  if (q >= NN * 16) return;
  int n = q >> 4;                                   // 16 quads per node
  float4 v = (n < NUSERS) ? uemb[q] : iemb[q - NUSERS * 16];
  float r = rsq[n] * W8SCALE;
  x0q[q] = f4q8(v.x * r, v.y * r, v.z * r, v.w * r);
}

// ---------------- bucket histogram: LDS-private, 293 global atomics per block -----------
__global__ __launch_bounds__(256) void k_bhist(const int* __restrict__ rows,
                                               int* __restrict__ bhist) {
  __shared__ int lh[NB];
  int t = threadIdx.x;
  for (int i = t; i < NB; i += 256) lh[i] = 0;
  __syncthreads();
  const int per = (NNZ + BHB - 1) / BHB;
  int base = blockIdx.x * per;
  int end = min(base + per, NNZ);
  for (int e = base + t; e < end; e += 256)
    atomicAdd(&lh[rows[e] >> BKSH], 1);
  __syncthreads();
  for (int i = t; i < NB; i += 256) {
    int c = lh[i];
    if (c) atomicAdd(&bhist[i], c);
  }
}

// ---------------- bucket scan (one block, 512 threads) ----------------
__global__ __launch_bounds__(512) void k_bscan(const int* __restrict__ bhist,
                                               int* __restrict__ bbase, int* __restrict__ bcur,
                                               int* __restrict__ row_ptr) {
  __shared__ int sc[512];
  int t = threadIdx.x;
  int v = (t < NB) ? bhist[t] : 0;
  sc[t] = v;
  __syncthreads();
  for (int off = 1; off < 512; off <<= 1) {
    int u = (t >= off) ? sc[t - off] : 0;
    __syncthreads();
    sc[t] += u;
    __syncthreads();
  }
  int ex = sc[t] - v;                  // exclusive prefix
  if (t < NB) { bbase[t] = ex; bcur[t] = ex; }
  if (t == NB - 1) { bbase[NB] = ex + v; row_ptr[NN] = ex + v; }  // == NNZ
}

// ---------------- bucket pass A: LDS counting-sort, packed 4-byte output ----------------
// packed word: col | (row&511)<<18   (col < 2^18, row-local < 2^9)
__global__ __launch_bounds__(256) void k_bucketA(const int* __restrict__ rows,
                                                 const int* __restrict__ cols,
                                                 int* __restrict__ bcur,
                                                 int* __restrict__ tmp) {
  __shared__ int lhist[NB];
  __shared__ int lscan[NB];
  __shared__ int ldelta[NB];
  __shared__ int lcnt[NB];
  __shared__ int2 ent[ACHUNK];        // x=packed col/rowlocal, y=ldelta
  int t = threadIdx.x;
  int base = blockIdx.x * ACHUNK;
  for (int b = t; b < NB; b += 256) { lhist[b] = 0; lcnt[b] = 0; }
  __syncthreads();
  int pkv[16], bkt[16];
  int nval = 0;
#pragma unroll
  for (int k = 0; k < 16; k++) {
    int e = base + t + k * 256;                 // coalesced
    if (e < NNZ) {
      int r = rows[e];
      pkv[k] = cols[e] | ((r & 511) << 18);
      bkt[k] = r >> BKSH;
      atomicAdd(&lhist[bkt[k]], 1);
      nval = k + 1;
    }
  }
  __syncthreads();
  if (t == 0) {
    int run = 0;
    for (int b = 0; b < NB; b++) { lscan[b] = run; run += lhist[b]; }
  }
  __syncthreads();
  for (int b = t; b < NB; b += 256) {
    int c = lhist[b];
    int g = (c > 0) ? atomicAdd(&bcur[b], c) : 0;
    ldelta[b] = g - lscan[b];
  }
  __syncthreads();
#pragma unroll
  for (int k = 0; k < 16; k++) {
    if (k < nval) {
      int b = bkt[k];
      int lp = atomicAdd(&lcnt[b], 1);
      ent[lscan[b] + lp] = make_int2(pkv[k], ldelta[b]);
    }
  }
  __syncthreads();
  int tot = min(ACHUNK, NNZ - base);
  for (int j = t; j < tot; j += 256) {
    int2 E = ent[j];
    tmp[E.y + j] = E.x;                        // contiguous run per bucket -> full lines
  }
}

// ---------------- bucket pass B: row_ptr + deg tables + final scatter ----------------
__global__ __launch_bounds__(512) void k_bucketB(const int* __restrict__ bbase,
                                                 const int* __restrict__ tmp,
                                                 int* __restrict__ ev,
                                                 int* __restrict__ row_ptr,
                                                 float* __restrict__ rsq,
                                                 float* __restrict__ sqd) {
  __shared__ int h[512], sc[512], c2[512], rstart[512];
  int b = blockIdx.x, t = threadIdx.x;
  int nbase = b << BKSH;
  h[t] = 0; c2[t] = 0;
  __syncthreads();
  int beg = bbase[b], end = bbase[b + 1];
  for (int j = beg + t; j < end; j += 512)
    atomicAdd(&h[tmp[j] >> 18], 1);
  __syncthreads();
  int v = h[t];
  sc[t] = v;
  __syncthreads();
  for (int off = 1; off < 512; off <<= 1) {
    int u = (t >= off) ? sc[t - off] : 0;
    __syncthreads();
    sc[t] += u;
    __syncthreads();
  }
  int rp = beg + sc[t] - v;            // exclusive scan -> row start
  rstart[t] = rp;
  int node = nbase + t;
  if (node < NN) {
    row_ptr[node] = rp;
    float fd = (float)v;
    rsq[node] = (v > 0) ? rsqrtf(fd) : 0.f;
    sqd[node] = sqrtf(fd);
  }
  __syncthreads();
  for (int j = beg + t; j < end; j += 512) {
    int w = tmp[j];
    int ln = w >> 18;
    int lp = atomicAdd(&c2[ln], 1);
    ev[rstart[ln] + lp] = w & CMASK;
  }
}

// ---------------- gather SpMV in scaled-w space (fp8 table, fp32 accumulate) ------------
// s_out = (LGAIN/deg) * sum_neighbors(s_in). wave/node, 4 grp x 16 lanes x 4 dims.
__global__ __launch_bounds__(256) void k_spmv(const int* __restrict__ row_ptr,
                                              const int* __restrict__ ev,
                                              const unsigned* __restrict__ cur,
                                              unsigned* __restrict__ nxt) {
  int lane = threadIdx.x & 63;
  int g = lane >> 4;                 // edge group 0..3 (edges ≡ g mod 4)
  int q4 = lane & 15;                // quad (4 dims) within row
  for (int node0 = blockIdx.x * 4 + (threadIdx.x >> 6); node0 < NN;
       node0 += SPMVB * 4) {
    int node = __builtin_amdgcn_readfirstlane(node0);
    int beg = row_ptr[node], end = row_ptr[node + 1];
    f32x2 a0 = {0.f, 0.f}, a1 = {0.f, 0.f};
    int e = beg + g;
    for (; e + 12 < end; e += 16) {  // 4 edges in flight per lane
      int c0 = __builtin_nontemporal_load(ev + e);
      int c1 = __builtin_nontemporal_load(ev + e + 4);
      int c2 = __builtin_nontemporal_load(ev + e + 8);
      int c3 = __builtin_nontemporal_load(ev + e + 12);
      unsigned W0 = cur[c0 * 16 + q4];
      unsigned W1 = cur[c1 * 16 + q4];
      unsigned W2 = cur[c2 * 16 + q4];
      unsigned W3 = cur[c3 * 16 + q4];
      a0 += __builtin_amdgcn_cvt_pk_f32_fp8(W0, false);
      a1 += __builtin_amdgcn_cvt_pk_f32_fp8(W0, true);
      a0 += __builtin_amdgcn_cvt_pk_f32_fp8(W1, false);
      a1 += __builtin_amdgcn_cvt_pk_f32_fp8(W1, true);
      a0 += __builtin_amdgcn_cvt_pk_f32_fp8(W2, false);
      a1 += __builtin_amdgcn_cvt_pk_f32_fp8(W2, true);
      a0 += __builtin_amdgcn_cvt_pk_f32_fp8(W3, false);
      a1 += __builtin_amdgcn_cvt_pk_f32_fp8(W3, true);
    }
    // predicated batch tail (<=3 edges per group) — all loads issue concurrently
    {
      bool p0 = e < end, p1 = e + 4 < end, p2 = e + 8 < end;
      int c0 = 0, c1 = 0, c2 = 0;
      if (p0) c0 = __builtin_nontemporal_load(ev + e);
      if (p1) c1 = __builtin_nontemporal_load(ev + e + 4);
      if (p2) c2 = __builtin_nontemporal_load(ev + e + 8);
      unsigned W0 = 0u, W1 = 0u, W2 = 0u;
      if (p0) W0 = cur[c0 * 16 + q4];
      if (p1) W1 = cur[c1 * 16 + q4];
      if (p2) W2 = cur[c2 * 16 + q4];
      a0 += __builtin_amdgcn_cvt_pk_f32_fp8(W0, false);
      a1 += __builtin_amdgcn_cvt_pk_f32_fp8(W0, true);
      a0 += __builtin_amdgcn_cvt_pk_f32_fp8(W1, false);
      a1 += __builtin_amdgcn_cvt_pk_f32_fp8(W1, true);
      a0 += __builtin_amdgcn_cvt_pk_f32_fp8(W2, false);
      a1 += __builtin_amdgcn_cvt_pk_f32_fp8(W2, true);
    }
    // reduce across the 4 edge groups
    a0.x += __shfl_xor(a0.x, 16); a0.y += __shfl_xor(a0.y, 16);
    a1.x += __shfl_xor(a1.x, 16); a1.y += __shfl_xor(a1.y, 16);
    a0.x += __shfl_xor(a0.x, 32); a0.y += __shfl_xor(a0.y, 32);
    a1.x += __shfl_xor(a1.x, 32); a1.y += __shfl_xor(a1.y, 32);
    if (g == 0) {
      float sc = (end > beg) ? LGAIN / (float)(end - beg) : 0.f;
      unsigned w = f4q8(a0.x * sc, a0.y * sc, a1.x * sc, a1.y * sc);
      __builtin_nontemporal_store(w, &nxt[node * 16 + q4]);
    }
  }
}

// ---------------- batch gather: ue = ALPHA*(x0 + sqd*(s1/4096 + s2/16384 + s3/65536)) ----
__global__ __launch_bounds__(256) void k_gather(const float4* __restrict__ uemb4,
                                                const float4* __restrict__ iemb4,
                                                const unsigned* __restrict__ x1q,
                                                const unsigned* __restrict__ x2q,
                                                const unsigned* __restrict__ x3q,
                                                const float* __restrict__ sqd,
                                                const int* __restrict__ user,
                                                const int* __restrict__ pos,
                                                const int* __restrict__ neg,
                                                float4* __restrict__ ue4,
                                                float4* __restrict__ pe4,
                                                float4* __restrict__ ne4,
                                                float* __restrict__ partR) {
  __shared__ float sred[256];
  const float G1 = 1.f / (W8SCALE * LGAIN);            // 1/4096
  const float G2 = 0.25f, G3 = 0.0625f;                // relative layer gains
  int t = threadIdx.x;
  int gid = blockIdx.x * 256 + t;    // BATCH*16 exact
  int i = gid >> 4, q = gid & 15;
  int u = user[i], p = pos[i], n = neg[i];
  int nu = u, np = NUSERS + p, nn = NUSERS + n;
  int qu = nu * 16 + q, qp = np * 16 + q, qn = nn * 16 + q;
  float4 eu = uemb4[qu];                       // x0 user (also reg term)
  float4 ep = iemb4[p * 16 + q];               // x0 pos  (also reg term)
  float4 en = iemb4[n * 16 + q];               // x0 neg  (also reg term)
  float ku = sqd[nu] * G1, kp = sqd[np] * G1, kn = sqd[nn] * G1;
  float4 a1 = q8f(x1q[qu]), a2 = q8f(x2q[qu]), a3 = q8f(x3q[qu]);
  float4 b1 = q8f(x1q[qp]), b2 = q8f(x2q[qp]), b3 = q8f(x3q[qp]);
  float4 c1 = q8f(x1q[qn]), c2 = q8f(x2q[qn]), c3 = q8f(x3q[qn]);
  float4 su = make_float4(ALPHA * (eu.x + ku * (a1.x + G2 * a2.x + G3 * a3.x)),
                          ALPHA * (eu.y + ku * (a1.y + G2 * a2.y + G3 * a3.y)),
                          ALPHA * (eu.z + ku * (a1.z + G2 * a2.z + G3 * a3.z)),
                          ALPHA * (eu.w + ku * (a1.w + G2 * a2.w + G3 * a3.w)));
  float4 sp = make_float4(ALPHA * (ep.x + kp * (b1.x + G2 * b2.x + G3 * b3.x)),
                          ALPHA * (ep.y + kp * (b1.y + G2 * b2.y + G3 * b3.y)),
                          ALPHA * (ep.z + kp * (b1.z + G2 * b2.z + G3 * b3.z)),
                          ALPHA * (ep.w + kp * (b1.w + G2 * b2.w + G3 * b3.w)));
  float4 sn = make_float4(ALPHA * (en.x + kn * (c1.x + G2 * c2.x + G3 * c3.x)),
                          ALPHA * (en.y + kn * (c1.y + G2 * c2.y + G3 * c3.y)),
                          ALPHA * (en.z + kn * (c1.z + G2 * c2.z + G3 * c3.z)),
                          ALPHA * (en.w + kn * (c1.w + G2 * c2.w + G3 * c3.w)));
  ue4[gid] = su;  pe4[gid] = sp;  ne4[gid] = sn;
  sred[t] = eu.x * eu.x + eu.y * eu.y + eu.z * eu.z + eu.w * eu.w
          + ep.x * ep.x + ep.y * ep.y + ep.z * ep.z + ep.w * ep.w
          + en.x * en.x + en.y * en.y + en.z * en.z + en.w * en.w;
  __syncthreads();
  for (int off = 128; off > 0; off >>= 1) {
    if (t < off) sred[t] += sred[t + off];
    __syncthreads();
  }
  if (t == 0) partR[blockIdx.x] = sred[0];
}

// ---------------- mixes, scores, row normalization (wave per row); also emit bf16 ----------
__global__ void k_mixnorm(const float* __restrict__ ue, const float* __restrict__ pe,
                          const float* __restrict__ ne, const float* __restrict__ beta_u,
                          const float* __restrict__ beta_i, const int* __restrict__ perm,
                          float* __restrict__ An_u, float* __restrict__ Pn_u,
                          float* __restrict__ An_p, float* __restrict__ Pn_p,
                          unsigned short* __restrict__ An_uh, unsigned short* __restrict__ Pn_uh,
                          unsigned short* __restrict__ An_ph, unsigned short* __restrict__ Pn_ph,
                          float* __restrict__ pos_sc, float* __restrict__ neg_sc,
                          float* __restrict__ nms) {
  int gid = blockIdx.x * blockDim.x + threadIdx.x;   // BATCH*64 exact
  int i = gid >> 6, d = gid & 63;
  int pi = perm[i];
  float uei = ue[i * DIM + d], pei = pe[i * DIM + d], nei = ne[i * DIM + d];
  float ud = ue[pi * DIM + d], pd = pe[pi * DIM + d], nd = ne[pi * DIM + d];
  float bu = beta_u[i], bi = beta_i[i];
  float um = bu * uei + (1.f - bu) * ud;
  float pm = bi * pei + (1.f - bi) * pd;
  float nm = bi * nei + (1.f - bi) * nd;
  float r0 = uei * pei, r1 = uei * nei, r2 = uei * nm;
  float r3 = uei * uei, r4 = um * um, r5 = pei * pei, r6 = pm * pm;
  for (int o = 32; o > 0; o >>= 1) {
    r0 += __shfl_xor(r0, o); r1 += __shfl_xor(r1, o); r2 += __shfl_xor(r2, o);
    r3 += __shfl_xor(r3, o); r4 += __shfl_xor(r4, o); r5 += __shfl_xor(r5, o);
    r6 += __shfl_xor(r6, o);
  }
  if (d == 0) { pos_sc[i] = r0; neg_sc[i] = r1; nms[i] = r2; }
  float inu  = 1.f / fmaxf(sqrtf(r3), 1e-12f);
  float inum = 1.f / fmaxf(sqrtf(r4), 1e-12f);
  float inp  = 1.f / fmaxf(sqrtf(r5), 1e-12f);
  float inpm = 1.f / fmaxf(sqrtf(r6), 1e-12f);
  float a0 = uei * inu, p0 = um * inum, a1 = pei * inp, p1 = pm * inpm;
  An_u[gid] = a0;  Pn_u[gid] = p0;  An_p[gid] = a1;  Pn_p[gid] = p1;
  An_uh[gid] = bf16r(a0); Pn_uh[gid] = bf16r(p0);
  An_ph[gid] = bf16r(a1); Pn_ph[gid] = bf16r(p1);
}

// ---------------- collective-mix: parallel partial sums (64 blocks) ----------------
__global__ void k_colpart(const float* __restrict__ ue, const float* __restrict__ pe,
                          const float* __restrict__ cu, const float* __restrict__ cp,
                          float* __restrict__ S) {
  __shared__ float smu[4][64], smp[4][64];
  int t = threadIdx.x, d = t & 63, q = t >> 6;
  int r0 = blockIdx.x * 64 + q * 16;
  float su = 0.f, sp = 0.f;
#pragma unroll 4
  for (int i = r0; i < r0 + 16; ++i) {
    su = fmaf(cu[i], ue[i * DIM + d], su);
    sp = fmaf(cp[i], pe[i * DIM + d], sp);
  }
  smu[q][d] = su; smp[q][d] = sp;
  __syncthreads();
  if (t < 64) {
    atomicAdd(&S[64 + d],  smu[0][d] + smu[1][d] + smu[2][d] + smu[3][d]);
    atomicAdd(&S[128 + d], smp[0][d] + smp[1][d] + smp[2][d] + smp[3][d]);
  }
}

// ---------------- colnorm + small sums (one block, 256 threads) ----------------
__global__ void k_colnorm(const float* __restrict__ beta_u, const float* __restrict__ beta_i,
                          const float* __restrict__ partR, float* __restrict__ S,
                          float* __restrict__ c_u, float* __restrict__ c_p) {
  __shared__ float a[256], b[256], c[256];
  int t = threadIdx.x;
  float su = 0.f, si = 0.f, sr = 0.f;
  for (int j = t; j < BATCH; j += 256) { su += beta_u[j]; si += beta_i[j]; }
  for (int j = t; j < NGB; j += 256) sr += partR[j];
  a[t] = su; b[t] = si; c[t] = sr;
  __syncthreads();
  for (int off = 128; off > 0; off >>= 1) {
    if (t < off) { a[t] += a[t + off]; b[t] += b[t + off]; c[t] += c[t + off]; }
    __syncthreads();
  }
  if (t == 0) { S[0] = c[0]; S[1] = a[0]; S[2] = b[0]; }
  // colnorm: waves 0,1 (uniform branch per wave)
  if (t < 128) {
    int d = t & 63;
    float v = (t < 64) ? S[64 + d] : S[128 + d];
    float n = wred64(v * v);
    float inv = 1.f / fmaxf(sqrtf(n), 1e-12f);
    if (t < 64) c_u[d] = v * inv;
    else        c_p[d] = v * inv;
  }
}

// ---------------- per-row sims (wave per row) ----------------
__global__ void k_sims(const float* __restrict__ An_u, const float* __restrict__ Pn_u,
                       const float* __restrict__ An_p, const float* __restrict__ Pn_p,
                       const float* __restrict__ c_u, const float* __restrict__ c_p,
                       const int* __restrict__ perm, const int* __restrict__ inv,
                       float* __restrict__ dis_u, float* __restrict__ col_u,
                       float* __restrict__ posd_u, float* __restrict__ cross_u,
                       float* __restrict__ dis_p, float* __restrict__ col_p,
                       float* __restrict__ posd_p, float* __restrict__ cross_p) {
  int gid = blockIdx.x * blockDim.x + threadIdx.x;
  int r = gid >> 6, d = gid & 63;
  int pr = perm[r], ir = inv[r];
  float au = An_u[r * DIM + d], pu = Pn_u[r * DIM + d];
  float ap = An_p[r * DIM + d], pp = Pn_p[r * DIM + d];
  float r0 = au * An_u[pr * DIM + d];
  float r1 = au * c_u[d];
  float r2 = au * pu;
  float r3 = au * Pn_u[ir * DIM + d];
  float r4 = ap * An_p[pr * DIM + d];
  float r5 = ap * c_p[d];
  float r6 = ap * pp;
  float r7 = ap * Pn_p[ir * DIM + d];
  for (int o = 32; o > 0; o >>= 1) {
    r0 += __shfl_xor(r0, o); r1 += __shfl_xor(r1, o); r2 += __shfl_xor(r2, o);
    r3 += __shfl_xor(r3, o); r4 += __shfl_xor(r4, o); r5 += __shfl_xor(r5, o);
    r6 += __shfl_xor(r6, o); r7 += __shfl_xor(r7, o);
  }
  if (d == 0) {
    dis_u[r] = r0 * INVT; col_u[r] = r1 * INVT; posd_u[r] = r2 * INVT; cross_u[r] = r3 * INVT;
    dis_p[r] = r4 * INVT; col_p[r] = r5 * INVT; posd_p[r] = r6 * INVT; cross_p[r] = r7 * INVT;
  }
}

// ---------------- MFMA fused matmul + fixed-shift sumexp over G = An @ Pn^T / T ----------
__global__ __launch_bounds__(256) void k_lse_mfma(const unsigned short* __restrict__ Anh,
                                                  const unsigned short* __restrict__ Pnh,
                                                  float* __restrict__ s_row) {
  const float C1 = INVT * 1.4426950408889634f;   // INVT*log2(e)
  int rb = blockIdx.x >> 3, cb = blockIdx.x & 7;
  int w = threadIdx.x >> 6, lane = threadIdx.x & 63;
  int r0 = rb * 64 + w * 16;
  int arow = r0 + (lane & 15);
  int koff = (lane >> 4) * 8;
  v8s a_lo = *(const v8s*)&Anh[arow * DIM + koff];
  v8s a_hi = *(const v8s*)&Anh[arow * DIM + koff + 32];
  float s0 = 0.f, s1 = 0.f, s2 = 0.f, s3 = 0.f;
  int cbase = cb * 512;
#pragma unroll 2
  for (int c0 = cbase; c0 < cbase + 512; c0 += 16) {
    int brow = c0 + (lane & 15);
    v8s b_lo = *(const v8s*)&Pnh[brow * DIM + koff];
    v8s b_hi = *(const v8s*)&Pnh[brow * DIM + koff + 32];
    f32x4 acc = {0.f, 0.f, 0.f, 0.f};
    acc = __builtin_amdgcn_mfma_f32_16x16x32_bf16(a_lo, b_lo, acc, 0, 0, 0);
    acc = __builtin_amdgcn_mfma_f32_16x16x32_bf16(a_hi, b_hi, acc, 0, 0, 0);
    s0 += exp2f(fmaf(acc[0], C1, -C1));
    s1 += exp2f(fmaf(acc[1], C1, -C1));
    s2 += exp2f(fmaf(acc[2], C1, -C1));
    s3 += exp2f(fmaf(acc[3], C1, -C1));
  }
  // sum the 16 col-slots of each row (C/D: col=lane&15, row=(lane>>4)*4+reg)
  for (int o = 1; o <= 8; o <<= 1) {
    s0 += __shfl_xor(s0, o); s1 += __shfl_xor(s1, o);
    s2 += __shfl_xor(s2, o); s3 += __shfl_xor(s3, o);
  }
  if ((lane & 15) == 0) {
    int rq = r0 + (lane >> 4) * 4;
    atomicAdd(&s_row[rq + 0], s0);
    atomicAdd(&s_row[rq + 1], s1);
    atomicAdd(&s_row[rq + 2], s2);
    atomicAdd(&s_row[rq + 3], s3);
  }
}

// ---------------- final combine (single block) — OUTPUT IS FLOAT32 ----------------
__global__ void k_final(const float* __restrict__ m_u, const float* __restrict__ s_u,
                        const float* __restrict__ dis_u, const float* __restrict__ col_u,
                        const float* __restrict__ posd_u, const float* __restrict__ cross_u,
                        const float* __restrict__ m_p, const float* __restrict__ s_p,
                        const float* __restrict__ dis_p, const float* __restrict__ col_p,
                        const float* __restrict__ posd_p, const float* __restrict__ cross_p,
                        const float* __restrict__ pos_sc, const float* __restrict__ neg_sc,
                        const float* __restrict__ nms, const int* __restrict__ inv,
                        const float* __restrict__ S, float* __restrict__ out) {
  __shared__ float red[6][256];
  int t = threadIdx.x;
  float lpu = 0.f, lnu = 0.f, lpp = 0.f, lnp = 0.f, bp = 0.f, bn = 0.f;
  for (int r = t; r < BATCH; r += 256) {
    int ir = inv[r];
    {
      float M = m_u[r], Sv = s_u[r];
      float d2 = col_u[r];
      float d1 = dis_u[r];
      float nm2 = fmaxf(M, fmaxf(d1, d2));
      float ss = Sv * __expf(M - nm2) + __expf(d1 - nm2) + __expf(d2 - nm2);
      lpu += nm2 + logf(ss) - posd_u[r];
      float d1n = dis_u[ir];
      nm2 = fmaxf(M, fmaxf(d1n, d2));
      ss = Sv * __expf(M - nm2) + __expf(d1n - nm2) + __expf(d2 - nm2);
      lnu += nm2 + logf(ss) - cross_u[r];
    }
    {
      float M = m_p[r], Sv = s_p[r];
      float d2 = col_p[r];
      float d1 = dis_p[r];
      float nm2 = fmaxf(M, fmaxf(d1, d2));
      float ss = Sv * __expf(M - nm2) + __expf(d1 - nm2) + __expf(d2 - nm2);
      lpp += nm2 + logf(ss) - posd_p[r];
      float d1n = dis_p[ir];
      nm2 = fmaxf(M, fmaxf(d1n, d2));
      ss = Sv * __expf(M - nm2) + __expf(d1n - nm2) + __expf(d2 - nm2);
      lnp += nm2 + logf(ss) - cross_p[r];
    }
    float ps = pos_sc[r];
    bp += softplusf(neg_sc[r] - ps);
    bn += softplusf(nms[r] - ps);
  }
  red[0][t] = lpu; red[1][t] = lnu; red[2][t] = lpp;
  red[3][t] = lnp; red[4][t] = bp;  red[5][t] = bn;
  __syncthreads();
  for (int off = 128; off > 0; off >>= 1) {
    if (t < off)
      for (int c = 0; c < 6; c++) red[c][t] += red[c][t + off];
    __syncthreads();
  }
  if (t == 0) {
    const float inv_b = 1.f / (float)BATCH;
    float mbu = S[1] * inv_b;            // mean(beta_u)
    float b   = S[2] * inv_b;            // mean(beta_i)
    float cl_u = mbu * (red[0][0] * inv_b) + (1.f - mbu) * (red[1][0] * inv_b);
    float cl_p = b   * (red[2][0] * inv_b) + (1.f - b)   * (red[3][0] * inv_b);
    float main_m = b * (red[4][0] * inv_b) + (1.f - b) * (red[5][0] * inv_b);
    float reg = REGC * S[0] * inv_b;
    float loss = main_m + LAMBDA * (cl_u + cl_p) + reg;
    out[0] = loss;                       // float32
  }
}

extern "C" void kernel_launch(void* const* d_in, const int* in_sizes, int n_in,
                              void* d_out, int out_size, void* d_ws, size_t ws_size,
                              hipStream_t stream) {
  const float* uemb   = (const float*)d_in[0];
  const float* iemb   = (const float*)d_in[1];
  const int*   rows   = (const int*)d_in[2];
  const int*   cols   = (const int*)d_in[3];
  const int*   user   = (const int*)d_in[5];
  const int*   pos    = (const int*)d_in[6];
  const int*   neg    = (const int*)d_in[7];
  const float* beta_u = (const float*)d_in[8];
  const float* beta_i = (const float*)d_in[9];
  const int*   perm   = (const int*)d_in[10];
  const float* cu     = (const float*)d_in[11];
  const float* cp     = (const float*)d_in[12];

  char* w = (char*)d_ws;
  size_t off = 0;
  auto alloc = [&](size_t bytes) -> char* {
    char* p = w + off;
    off += (bytes + 255) & ~(size_t)255;
    return p;
  };
  unsigned* x0q = (unsigned*)alloc((size_t)NN * 16 * 4);   // fp8 quads: 9.6MB each
  unsigned* x1q = (unsigned*)alloc((size_t)NN * 16 * 4);
  unsigned* x2q = (unsigned*)alloc((size_t)NN * 16 * 4);
  unsigned* x3q = (unsigned*)alloc((size_t)NN * 16 * 4);
  int*   ev      = (int*)  alloc((size_t)NNZ * 4);
  int*   row_ptr = (int*)  alloc((size_t)(NN + 1) * 4);
  float* rsq     = (float*)alloc((size_t)NN * 4);
  float* sqd     = (float*)alloc((size_t)NN * 4);
  int*   bhist   = (int*)  alloc((size_t)NB * 4);
  int*   bbase   = (int*)  alloc((size_t)(NB + 1) * 4);
  int*   bcur    = (int*)  alloc((size_t)NB * 4);
  float* partR   = (float*)alloc((size_t)NGB * 4);
  float* ue      = (float*)alloc((size_t)BATCH * DIM * 4);
  float* pe      = (float*)alloc((size_t)BATCH * DIM * 4);
  float* ne      = (float*)alloc((size_t)BATCH * DIM * 4);
  float* An_u    = (float*)alloc((size_t)BATCH * DIM * 4);
  float* Pn_u    = (float*)alloc((size_t)BATCH * DIM * 4);
  float* An_p    = (float*)alloc((size_t)BATCH * DIM * 4);
  float* Pn_p    = (float*)alloc((size_t)BATCH * DIM * 4);
  unsigned short* An_uh = (unsigned short*)alloc((size_t)BATCH * DIM * 2);
  unsigned short* Pn_uh = (unsigned short*)alloc((size_t)BATCH * DIM * 2);
  unsigned short* An_ph = (unsigned short*)alloc((size_t)BATCH * DIM * 2);
  unsigned short* Pn_ph = (unsigned short*)alloc((size_t)BATCH * DIM * 2);
  float* pos_sc  = (float*)alloc((size_t)BATCH * 4);
  float* neg_sc  = (float*)alloc((size_t)BATCH * 4);
  float* nms     = (float*)alloc((size_t)BATCH * 4);
  float* dis_u   = (float*)alloc((size_t)BATCH * 4);
  float* col_u   = (float*)alloc((size_t)BATCH * 4);
  float* posd_u  = (float*)alloc((size_t)BATCH * 4);
  float* cross_u = (float*)alloc((size_t)BATCH * 4);
  float* m_u     = (float*)alloc((size_t)BATCH * 4);
  float* s_u     = (float*)alloc((size_t)BATCH * 4);
  float* dis_p   = (float*)alloc((size_t)BATCH * 4);
  float* col_p   = (float*)alloc((size_t)BATCH * 4);
  float* posd_p  = (float*)alloc((size_t)BATCH * 4);
  float* cross_p = (float*)alloc((size_t)BATCH * 4);
  float* m_p     = (float*)alloc((size_t)BATCH * 4);
  float* s_p     = (float*)alloc((size_t)BATCH * 4);
  int*   invp    = (int*)  alloc((size_t)BATCH * 4);
  float* c_u     = (float*)alloc(256);
  float* c_p     = (float*)alloc(256);
  float* S       = (float*)alloc(1024);

  // tmp (int per edge, 12.8MB) aliases x0q+x1q (19.2MB) — dead until k_inith,
  // which runs AFTER the CSR build.
  int* tmp = (int*)x0q;

  // 1. zero bucket hist + preset LSE state + invperm
  k_zero<<<(NN + 255) / 256, 256, 0, stream>>>(bhist, S, m_u, s_u, m_p, s_p, perm, invp);
  // 2. CSR build: bucket hist -> scan -> 2-pass bucket sort (row_ptr + deg tables in pass B)
  k_bhist<<<BHB, 256, 0, stream>>>(rows, bhist);
  k_bscan<<<1, 512, 0, stream>>>(bhist, bbase, bcur, row_ptr);
  k_bucketA<<<(NNZ + ACHUNK - 1) / ACHUNK, 256, 0, stream>>>(rows, cols, bcur, tmp);
  k_bucketB<<<NB, 512, 0, stream>>>(bbase, tmp, ev, row_ptr, rsq, sqd);
  // 3. init s0 = 1024 * rsqrt(deg) * x0 (fp8)
  k_inith<<<(NN * 16 + 255) / 256, 256, 0, stream>>>((const float4*)uemb, (const float4*)iemb,
                                                     rsq, x0q);
  // 4. three GCN layers in scaled-w space (fp8 table, fp32 accumulate, gain 4/layer)
  k_spmv<<<SPMVB, 256, 0, stream>>>(row_ptr, ev, x0q, x1q);
  k_spmv<<<SPMVB, 256, 0, stream>>>(row_ptr, ev, x1q, x2q);
  k_spmv<<<SPMVB, 256, 0, stream>>>(row_ptr, ev, x2q, x3q);
  // 5. batch gather (exact power-of-2 unscaling, batch rows only)
  k_gather<<<NGB, 256, 0, stream>>>((const float4*)uemb, (const float4*)iemb,
                                    x1q, x2q, x3q, sqd, user, pos, neg,
                                    (float4*)ue, (float4*)pe, (float4*)ne, partR);
  // 6. mixes, scores, normalization (+ bf16 copies for MFMA)
  k_mixnorm<<<(BATCH * DIM) / 256, 256, 0, stream>>>(ue, pe, ne, beta_u, beta_i, perm,
                                                     An_u, Pn_u, An_p, Pn_p,
                                                     An_uh, Pn_uh, An_ph, Pn_ph,
                                                     pos_sc, neg_sc, nms);
  k_colpart<<<BATCH / 64, 256, 0, stream>>>(ue, pe, cu, cp, S);
  k_colnorm<<<1, 256, 0, stream>>>(beta_u, beta_i, partR, S, c_u, c_p);
  k_sims<<<(BATCH * DIM) / 256, 256, 0, stream>>>(An_u, Pn_u, An_p, Pn_p, c_u, c_p,
                                                  perm, invp,
                                                  dis_u, col_u, posd_u, cross_u,
                                                  dis_p, col_p, posd_p, cross_p);
  // 7. MFMA matmul + fixed-shift sumexp (user side, pos side)
  k_lse_mfma<<<512, 256, 0, stream>>>(An_uh, Pn_uh, s_u);
  k_lse_mfma<<<512, 256, 0, stream>>>(An_ph, Pn_ph, s_p);
  // 8. final combine
  k_final<<<1, 256, 0, stream>>>(m_u, s_u, dis_u, col_u, posd_u, cross_u,
                                 m_p, s_p, dis_p, col_p, posd_p, cross_p,
                                 pos_sc, neg_sc, nms, invp, S,
                                 (float*)d_out);
}

// Round 13
// 318.523 us; speedup vs baseline: 1.0945x; 1.0945x over previous
//
#include <hip/hip_runtime.h>
#include <hip/hip_bf16.h>
#include <hip/hip_fp16.h>

#define NUSERS 100000
#define NITEMS 50000
#define NN     150001          // total nodes
#define NNZ    3200000         // 2 * NNZ_INTER
#define BATCH  4096
#define DIM    64
#define ND     (NN * DIM)
#define ALPHA  0.25f           // 1/(N_LAYERS+1)
#define INVT   5.0f            // 1/TEMP
#define LAMBDA 0.1f
#define REGC   1.0e-4f
#define BKSH   9               // 512 nodes per bucket
#define NB     293             // ceil(150001/512)
#define ACHUNK 4096            // edges per bucketA block
#define M0     5.0f            // fixed LSE shift: logits = sim/T ∈ [-5,5]
#define NGB    256             // k_gather blocks (BATCH*16/256)
#define BHB    256             // k_bhist blocks
#define CMASK  0x3FFFF         // 18-bit col mask
#define SPMVB  2048            // k_spmv grid (8 blocks/CU -> 32 waves/CU)

typedef __attribute__((ext_vector_type(8))) short v8s;    // 8 bf16 (4 VGPRs)
typedef __attribute__((ext_vector_type(4))) float f32x4;  // MFMA acc

union H2U { unsigned u; __half2 h; };
__device__ __forceinline__ __half2 u2h(unsigned x) { H2U t; t.u = x; return t.h; }
__device__ __forceinline__ unsigned h2u(__half2 h) { H2U t; t.h = h; return t.u; }
__device__ __forceinline__ __half2 h2shfl(__half2 v, int m) {
  return u2h((unsigned)__shfl_xor((int)h2u(v), m));
}

__device__ __forceinline__ float wred64(float v) {
  for (int o = 32; o > 0; o >>= 1) v += __shfl_xor(v, o);
  return v;
}

__device__ __forceinline__ float softplusf(float x) {
  return (x > 20.f) ? x : log1pf(__expf(x));
}

__device__ __forceinline__ unsigned short bf16r(float v) {
  unsigned x = __float_as_uint(v);
  return (unsigned short)((x + 0x7fff + ((x >> 16) & 1)) >> 16);   // RNE
}

// fp16 quad (uint2 = 4 halves) -> float4
__device__ __forceinline__ float4 h4f(uint2 u) {
  float2 lo = __half22float2(u2h(u.x));
  float2 hi = __half22float2(u2h(u.y));
  return make_float4(lo.x, lo.y, hi.x, hi.y);
}

// ---------------- zero scratch + preset LSE state + invperm ----------------
__global__ void k_zero(int* __restrict__ bhist, float* __restrict__ S,
                       float* __restrict__ m_u, float* __restrict__ s_u,
                       float* __restrict__ m_p, float* __restrict__ s_p,
                       const int* __restrict__ perm, int* __restrict__ inv) {
  int i = blockIdx.x * blockDim.x + threadIdx.x;
  if (i < NB) bhist[i] = 0;
  if (i < 256) S[i] = 0.f;
  if (i < BATCH) {
    s_u[i] = 0.f; s_p[i] = 0.f; m_u[i] = M0; m_p[i] = M0;
    inv[perm[i]] = i;
  }
}

// ---------------- w0 = rsqrt(deg) * concat(user_emb, item_emb), fp16 ----------------
__global__ void k_inith(const float4* __restrict__ uemb, const float4* __restrict__ iemb,
                        const float* __restrict__ rsq, uint2* __restrict__ x0h) {
  int q = blockIdx.x * blockDim.x + threadIdx.x;   // quads: ND/4
  if (q >= ND / 4) return;
  int n = q >> 4;                                   // 16 quads per node
  float4 v = (n < NUSERS) ? uemb[q] : iemb[q - NUSERS * 16];
  float r = rsq[n];
  x0h[q] = make_uint2(h2u(__floats2half2_rn(v.x * r, v.y * r)),
                      h2u(__floats2half2_rn(v.z * r, v.w * r)));
}

// ---------------- bucket histogram: LDS-private, 293 global atomics per block -----------
__global__ __launch_bounds__(256) void k_bhist(const int* __restrict__ rows,
                                               int* __restrict__ bhist) {
  __shared__ int lh[NB];
  int t = threadIdx.x;
  for (int i = t; i < NB; i += 256) lh[i] = 0;
  __syncthreads();
  const int per = (NNZ + BHB - 1) / BHB;
  int base = blockIdx.x * per;
  int end = min(base + per, NNZ);
  for (int e = base + t; e < end; e += 256)
    atomicAdd(&lh[rows[e] >> BKSH], 1);
  __syncthreads();
  for (int i = t; i < NB; i += 256) {
    int c = lh[i];
    if (c) atomicAdd(&bhist[i], c);
  }
}

// ---------------- bucket scan (one block, 512 threads) ----------------
__global__ __launch_bounds__(512) void k_bscan(const int* __restrict__ bhist,
                                               int* __restrict__ bbase, int* __restrict__ bcur,
                                               int* __restrict__ row_ptr) {
  __shared__ int sc[512];
  int t = threadIdx.x;
  int v = (t < NB) ? bhist[t] : 0;
  sc[t] = v;
  __syncthreads();
  for (int off = 1; off < 512; off <<= 1) {
    int u = (t >= off) ? sc[t - off] : 0;
    __syncthreads();
    sc[t] += u;
    __syncthreads();
  }
  int ex = sc[t] - v;                  // exclusive prefix
  if (t < NB) { bbase[t] = ex; bcur[t] = ex; }
  if (t == NB - 1) { bbase[NB] = ex + v; row_ptr[NN] = ex + v; }  // == NNZ
}

// ---------------- bucket pass A: LDS counting-sort, packed 4-byte output ----------------
// packed word: col | (row&511)<<18   (col < 2^18, row-local < 2^9)
__global__ __launch_bounds__(256) void k_bucketA(const int* __restrict__ rows,
                                                 const int* __restrict__ cols,
                                                 int* __restrict__ bcur,
                                                 int* __restrict__ tmp) {
  __shared__ int lhist[NB];
  __shared__ int lscan[NB];
  __shared__ int ldelta[NB];
  __shared__ int lcnt[NB];
  __shared__ int2 ent[ACHUNK];        // x=packed col/rowlocal, y=ldelta
  int t = threadIdx.x;
  int base = blockIdx.x * ACHUNK;
  for (int b = t; b < NB; b += 256) { lhist[b] = 0; lcnt[b] = 0; }
  __syncthreads();
  int pkv[16], bkt[16];
  int nval = 0;
#pragma unroll
  for (int k = 0; k < 16; k++) {
    int e = base + t + k * 256;                 // coalesced
    if (e < NNZ) {
      int r = rows[e];
      pkv[k] = cols[e] | ((r & 511) << 18);
      bkt[k] = r >> BKSH;
      atomicAdd(&lhist[bkt[k]], 1);
      nval = k + 1;
    }
  }
  __syncthreads();
  if (t == 0) {
    int run = 0;
    for (int b = 0; b < NB; b++) { lscan[b] = run; run += lhist[b]; }
  }
  __syncthreads();
  for (int b = t; b < NB; b += 256) {
    int c = lhist[b];
    int g = (c > 0) ? atomicAdd(&bcur[b], c) : 0;
    ldelta[b] = g - lscan[b];
  }
  __syncthreads();
#pragma unroll
  for (int k = 0; k < 16; k++) {
    if (k < nval) {
      int b = bkt[k];
      int lp = atomicAdd(&lcnt[b], 1);
      ent[lscan[b] + lp] = make_int2(pkv[k], ldelta[b]);
    }
  }
  __syncthreads();
  int tot = min(ACHUNK, NNZ - base);
  for (int j = t; j < tot; j += 256) {
    int2 E = ent[j];
    tmp[E.y + j] = E.x;                        // contiguous run per bucket -> full lines
  }
}

// ---------------- bucket pass B: row_ptr + deg tables + final scatter ----------------
__global__ __launch_bounds__(512) void k_bucketB(const int* __restrict__ bbase,
                                                 const int* __restrict__ tmp,
                                                 int* __restrict__ ev,
                                                 int* __restrict__ row_ptr,
                                                 float* __restrict__ rsq,
                                                 float* __restrict__ sqd) {
  __shared__ int h[512], sc[512], c2[512], rstart[512];
  int b = blockIdx.x, t = threadIdx.x;
  int nbase = b << BKSH;
  h[t] = 0; c2[t] = 0;
  __syncthreads();
  int beg = bbase[b], end = bbase[b + 1];
  for (int j = beg + t; j < end; j += 512)
    atomicAdd(&h[tmp[j] >> 18], 1);
  __syncthreads();
  int v = h[t];
  sc[t] = v;
  __syncthreads();
  for (int off = 1; off < 512; off <<= 1) {
    int u = (t >= off) ? sc[t - off] : 0;
    __syncthreads();
    sc[t] += u;
    __syncthreads();
  }
  int rp = beg + sc[t] - v;            // exclusive scan -> row start
  rstart[t] = rp;
  int node = nbase + t;
  if (node < NN) {
    row_ptr[node] = rp;
    float fd = (float)v;
    rsq[node] = (v > 0) ? rsqrtf(fd) : 0.f;
    sqd[node] = sqrtf(fd);
  }
  __syncthreads();
  for (int j = beg + t; j < end; j += 512) {
    int w = tmp[j];
    int ln = w >> 18;
    int lp = atomicAdd(&c2[ln], 1);
    ev[rstart[ln] + lp] = w & CMASK;
  }
}

// ---------------- gather SpMV in w-space: wave-parallel ev load + shuffle distribution ---
// w_out = (1/deg) * sum_neighbors(w_in).  Per 64-edge chunk: ONE ev VMEM (coalesced),
// cols distributed to 16-lane gather groups via ds_bpermute (off the TA path).
__global__ __launch_bounds__(256) void k_spmv(const int* __restrict__ row_ptr,
                                              const int* __restrict__ ev,
                                              const unsigned short* __restrict__ cur,
                                              unsigned short* __restrict__ nxt) {
  int lane = threadIdx.x & 63;
  int g = lane >> 4;                 // gather group 0..3
  int d4 = (lane & 15) << 2;         // 4 dims per lane
  for (int node0 = blockIdx.x * 4 + (threadIdx.x >> 6); node0 < NN;
       node0 += SPMVB * 4) {
    int node = __builtin_amdgcn_readfirstlane(node0);
    int beg = row_ptr[node], end = row_ptr[node + 1];
    int deg = end - beg;
    __half2 a0 = __float2half2_rn(0.f);
    __half2 a1 = a0;
    for (int base = 0; base < deg; base += 64) {
      int idx = base + lane;
      int col = 0;
      if (idx < deg) col = ev[beg + idx];        // ONE VMEM per 64 edges
      int cnt = min(deg - base, 64);
      int nit = (cnt + 15) >> 4;                 // 16 edges per iteration
      for (int it = 0; it < nit; ++it) {
        int e0 = it * 16 + g;                    // group g's 4 edges this iter
        int e1 = e0 + 4, e2 = e0 + 8, e3 = e0 + 12;
        int c0 = __shfl(col, e0);
        int c1 = __shfl(col, e1);
        int c2 = __shfl(col, e2);
        int c3 = __shfl(col, e3);
        uint2 H0 = make_uint2(0u, 0u), H1 = H0, H2 = H0, H3 = H0;
        if (e0 < cnt) H0 = *(const uint2*)&cur[c0 * DIM + d4];
        if (e1 < cnt) H1 = *(const uint2*)&cur[c1 * DIM + d4];
        if (e2 < cnt) H2 = *(const uint2*)&cur[c2 * DIM + d4];
        if (e3 < cnt) H3 = *(const uint2*)&cur[c3 * DIM + d4];
        a0 = __hadd2(a0, u2h(H0.x)); a1 = __hadd2(a1, u2h(H0.y));
        a0 = __hadd2(a0, u2h(H1.x)); a1 = __hadd2(a1, u2h(H1.y));
        a0 = __hadd2(a0, u2h(H2.x)); a1 = __hadd2(a1, u2h(H2.y));
        a0 = __hadd2(a0, u2h(H3.x)); a1 = __hadd2(a1, u2h(H3.y));
      }
    }
    // reduce across the 4 gather groups (packed fp16 adds)
    a0 = __hadd2(a0, h2shfl(a0, 16)); a1 = __hadd2(a1, h2shfl(a1, 16));
    a0 = __hadd2(a0, h2shfl(a0, 32)); a1 = __hadd2(a1, h2shfl(a1, 32));
    if (g == 0) {
      float invd = (deg > 0) ? 1.f / (float)deg : 0.f;
      __half2 iv = __float2half2_rn(invd);
      *(uint2*)&nxt[node * DIM + d4] =
          make_uint2(h2u(__hmul2(a0, iv)), h2u(__hmul2(a1, iv)));
    }
  }
}

// ---------------- batch gather: ue/pe/ne = ALPHA*(x0 + sqrt(deg)*(w1+w2+w3)) ------------
__global__ __launch_bounds__(256) void k_gather(const float4* __restrict__ uemb4,
                                                const float4* __restrict__ iemb4,
                                                const uint2* __restrict__ x1h,
                                                const uint2* __restrict__ x2h,
                                                const uint2* __restrict__ x3h,
                                                const float* __restrict__ sqd,
                                                const int* __restrict__ user,
                                                const int* __restrict__ pos,
                                                const int* __restrict__ neg,
                                                float4* __restrict__ ue4,
                                                float4* __restrict__ pe4,
                                                float4* __restrict__ ne4,
                                                float* __restrict__ partR) {
  __shared__ float sred[256];
  int t = threadIdx.x;
  int gid = blockIdx.x * 256 + t;    // BATCH*16 exact
  int i = gid >> 4, q = gid & 15;
  int u = user[i], p = pos[i], n = neg[i];
  int nu = u, np = NUSERS + p, nn = NUSERS + n;
  int qu = nu * 16 + q, qp = np * 16 + q, qn = nn * 16 + q;
  float4 eu = uemb4[qu];                       // x0 user (also reg term)
  float4 ep = iemb4[p * 16 + q];               // x0 pos  (also reg term)
  float4 en = iemb4[n * 16 + q];               // x0 neg  (also reg term)
  float su_ = sqd[nu], sp_ = sqd[np], sn_ = sqd[nn];
  float4 a1 = h4f(x1h[qu]), a2 = h4f(x2h[qu]), a3 = h4f(x3h[qu]);
  float4 b1 = h4f(x1h[qp]), b2 = h4f(x2h[qp]), b3 = h4f(x3h[qp]);
  float4 c1 = h4f(x1h[qn]), c2 = h4f(x2h[qn]), c3 = h4f(x3h[qn]);
  float4 su = make_float4(ALPHA * (eu.x + su_ * (a1.x + a2.x + a3.x)),
                          ALPHA * (eu.y + su_ * (a1.y + a2.y + a3.y)),
                          ALPHA * (eu.z + su_ * (a1.z + a2.z + a3.z)),
                          ALPHA * (eu.w + su_ * (a1.w + a2.w + a3.w)));
  float4 sp = make_float4(ALPHA * (ep.x + sp_ * (b1.x + b2.x + b3.x)),
                          ALPHA * (ep.y + sp_ * (b1.y + b2.y + b3.y)),
                          ALPHA * (ep.z + sp_ * (b1.z + b2.z + b3.z)),
                          ALPHA * (ep.w + sp_ * (b1.w + b2.w + b3.w)));
  float4 sn = make_float4(ALPHA * (en.x + sn_ * (c1.x + c2.x + c3.x)),
                          ALPHA * (en.y + sn_ * (c1.y + c2.y + c3.y)),
                          ALPHA * (en.z + sn_ * (c1.z + c2.z + c3.z)),
                          ALPHA * (en.w + sn_ * (c1.w + c2.w + c3.w)));
  ue4[gid] = su;  pe4[gid] = sp;  ne4[gid] = sn;
  sred[t] = eu.x * eu.x + eu.y * eu.y + eu.z * eu.z + eu.w * eu.w
          + ep.x * ep.x + ep.y * ep.y + ep.z * ep.z + ep.w * ep.w
          + en.x * en.x + en.y * en.y + en.z * en.z + en.w * en.w;
  __syncthreads();
  for (int off = 128; off > 0; off >>= 1) {
    if (t < off) sred[t] += sred[t + off];
    __syncthreads();
  }
  if (t == 0) partR[blockIdx.x] = sred[0];
}

// ---------------- mixes, scores, row normalization (wave per row); also emit bf16 ----------
__global__ void k_mixnorm(const float* __restrict__ ue, const float* __restrict__ pe,
                          const float* __restrict__ ne, const float* __restrict__ beta_u,
                          const float* __restrict__ beta_i, const int* __restrict__ perm,
                          float* __restrict__ An_u, float* __restrict__ Pn_u,
                          float* __restrict__ An_p, float* __restrict__ Pn_p,
                          unsigned short* __restrict__ An_uh, unsigned short* __restrict__ Pn_uh,
                          unsigned short* __restrict__ An_ph, unsigned short* __restrict__ Pn_ph,
                          float* __restrict__ pos_sc, float* __restrict__ neg_sc,
                          float* __restrict__ nms) {
  int gid = blockIdx.x * blockDim.x + threadIdx.x;   // BATCH*64 exact
  int i = gid >> 6, d = gid & 63;
  int pi = perm[i];
  float uei = ue[i * DIM + d], pei = pe[i * DIM + d], nei = ne[i * DIM + d];
  float ud = ue[pi * DIM + d], pd = pe[pi * DIM + d], nd = ne[pi * DIM + d];
  float bu = beta_u[i], bi = beta_i[i];
  float um = bu * uei + (1.f - bu) * ud;
  float pm = bi * pei + (1.f - bi) * pd;
  float nm = bi * nei + (1.f - bi) * nd;
  float r0 = uei * pei, r1 = uei * nei, r2 = uei * nm;
  float r3 = uei * uei, r4 = um * um, r5 = pei * pei, r6 = pm * pm;
  for (int o = 32; o > 0; o >>= 1) {
    r0 += __shfl_xor(r0, o); r1 += __shfl_xor(r1, o); r2 += __shfl_xor(r2, o);
    r3 += __shfl_xor(r3, o); r4 += __shfl_xor(r4, o); r5 += __shfl_xor(r5, o);
    r6 += __shfl_xor(r6, o);
  }
  if (d == 0) { pos_sc[i] = r0; neg_sc[i] = r1; nms[i] = r2; }
  float inu  = 1.f / fmaxf(sqrtf(r3), 1e-12f);
  float inum = 1.f / fmaxf(sqrtf(r4), 1e-12f);
  float inp  = 1.f / fmaxf(sqrtf(r5), 1e-12f);
  float inpm = 1.f / fmaxf(sqrtf(r6), 1e-12f);
  float a0 = uei * inu, p0 = um * inum, a1 = pei * inp, p1 = pm * inpm;
  An_u[gid] = a0;  Pn_u[gid] = p0;  An_p[gid] = a1;  Pn_p[gid] = p1;
  An_uh[gid] = bf16r(a0); Pn_uh[gid] = bf16r(p0);
  An_ph[gid] = bf16r(a1); Pn_ph[gid] = bf16r(p1);
}

// ---------------- collective-mix: parallel partial sums (64 blocks) ----------------
__global__ void k_colpart(const float* __restrict__ ue, const float* __restrict__ pe,
                          const float* __restrict__ cu, const float* __restrict__ cp,
                          float* __restrict__ S) {
  __shared__ float smu[4][64], smp[4][64];
  int t = threadIdx.x, d = t & 63, q = t >> 6;
  int r0 = blockIdx.x * 64 + q * 16;
  float su = 0.f, sp = 0.f;
#pragma unroll 4
  for (int i = r0; i < r0 + 16; ++i) {
    su = fmaf(cu[i], ue[i * DIM + d], su);
    sp = fmaf(cp[i], pe[i * DIM + d], sp);
  }
  smu[q][d] = su; smp[q][d] = sp;
  __syncthreads();
  if (t < 64) {
    atomicAdd(&S[64 + d],  smu[0][d] + smu[1][d] + smu[2][d] + smu[3][d]);
    atomicAdd(&S[128 + d], smp[0][d] + smp[1][d] + smp[2][d] + smp[3][d]);
  }
}

// ---------------- colnorm + small sums (one block, 256 threads) ----------------
__global__ void k_colnorm(const float* __restrict__ beta_u, const float* __restrict__ beta_i,
                          const float* __restrict__ partR, float* __restrict__ S,
                          float* __restrict__ c_u, float* __restrict__ c_p) {
  __shared__ float a[256], b[256], c[256];
  int t = threadIdx.x;
  float su = 0.f, si = 0.f, sr = 0.f;
  for (int j = t; j < BATCH; j += 256) { su += beta_u[j]; si += beta_i[j]; }
  for (int j = t; j < NGB; j += 256) sr += partR[j];
  a[t] = su; b[t] = si; c[t] = sr;
  __syncthreads();
  for (int off = 128; off > 0; off >>= 1) {
    if (t < off) { a[t] += a[t + off]; b[t] += b[t + off]; c[t] += c[t + off]; }
    __syncthreads();
  }
  if (t == 0) { S[0] = c[0]; S[1] = a[0]; S[2] = b[0]; }
  // colnorm: waves 0,1 (uniform branch per wave)
  if (t < 128) {
    int d = t & 63;
    float v = (t < 64) ? S[64 + d] : S[128 + d];
    float n = wred64(v * v);
    float inv = 1.f / fmaxf(sqrtf(n), 1e-12f);
    if (t < 64) c_u[d] = v * inv;
    else        c_p[d] = v * inv;
  }
}

// ---------------- per-row sims (wave per row) ----------------
__global__ void k_sims(const float* __restrict__ An_u, const float* __restrict__ Pn_u,
                       const float* __restrict__ An_p, const float* __restrict__ Pn_p,
                       const float* __restrict__ c_u, const float* __restrict__ c_p,
                       const int* __restrict__ perm, const int* __restrict__ inv,
                       float* __restrict__ dis_u, float* __restrict__ col_u,
                       float* __restrict__ posd_u, float* __restrict__ cross_u,
                       float* __restrict__ dis_p, float* __restrict__ col_p,
                       float* __restrict__ posd_p, float* __restrict__ cross_p) {
  int gid = blockIdx.x * blockDim.x + threadIdx.x;
  int r = gid >> 6, d = gid & 63;
  int pr = perm[r], ir = inv[r];
  float au = An_u[r * DIM + d], pu = Pn_u[r * DIM + d];
  float ap = An_p[r * DIM + d], pp = Pn_p[r * DIM + d];
  float r0 = au * An_u[pr * DIM + d];
  float r1 = au * c_u[d];
  float r2 = au * pu;
  float r3 = au * Pn_u[ir * DIM + d];
  float r4 = ap * An_p[pr * DIM + d];
  float r5 = ap * c_p[d];
  float r6 = ap * pp;
  float r7 = ap * Pn_p[ir * DIM + d];
  for (int o = 32; o > 0; o >>= 1) {
    r0 += __shfl_xor(r0, o); r1 += __shfl_xor(r1, o); r2 += __shfl_xor(r2, o);
    r3 += __shfl_xor(r3, o); r4 += __shfl_xor(r4, o); r5 += __shfl_xor(r5, o);
    r6 += __shfl_xor(r6, o); r7 += __shfl_xor(r7, o);
  }
  if (d == 0) {
    dis_u[r] = r0 * INVT; col_u[r] = r1 * INVT; posd_u[r] = r2 * INVT; cross_u[r] = r3 * INVT;
    dis_p[r] = r4 * INVT; col_p[r] = r5 * INVT; posd_p[r] = r6 * INVT; cross_p[r] = r7 * INVT;
  }
}

// ---------------- MFMA fused matmul + fixed-shift sumexp over G = An @ Pn^T / T ----------
__global__ __launch_bounds__(256) void k_lse_mfma(const unsigned short* __restrict__ Anh,
                                                  const unsigned short* __restrict__ Pnh,
                                                  float* __restrict__ s_row) {
  const float C1 = INVT * 1.4426950408889634f;   // INVT*log2(e)
  int rb = blockIdx.x >> 3, cb = blockIdx.x & 7;
  int w = threadIdx.x >> 6, lane = threadIdx.x & 63;
  int r0 = rb * 64 + w * 16;
  int arow = r0 + (lane & 15);
  int koff = (lane >> 4) * 8;
  v8s a_lo = *(const v8s*)&Anh[arow * DIM + koff];
  v8s a_hi = *(const v8s*)&Anh[arow * DIM + koff + 32];
  float s0 = 0.f, s1 = 0.f, s2 = 0.f, s3 = 0.f;
  int cbase = cb * 512;
#pragma unroll 2
  for (int c0 = cbase; c0 < cbase + 512; c0 += 16) {
    int brow = c0 + (lane & 15);
    v8s b_lo = *(const v8s*)&Pnh[brow * DIM + koff];
    v8s b_hi = *(const v8s*)&Pnh[brow * DIM + koff + 32];
    f32x4 acc = {0.f, 0.f, 0.f, 0.f};
    acc = __builtin_amdgcn_mfma_f32_16x16x32_bf16(a_lo, b_lo, acc, 0, 0, 0);
    acc = __builtin_amdgcn_mfma_f32_16x16x32_bf16(a_hi, b_hi, acc, 0, 0, 0);
    s0 += exp2f(fmaf(acc[0], C1, -C1));
    s1 += exp2f(fmaf(acc[1], C1, -C1));
    s2 += exp2f(fmaf(acc[2], C1, -C1));
    s3 += exp2f(fmaf(acc[3], C1, -C1));
  }
  // sum the 16 col-slots of each row (C/D: col=lane&15, row=(lane>>4)*4+reg)
  for (int o = 1; o <= 8; o <<= 1) {
    s0 += __shfl_xor(s0, o); s1 += __shfl_xor(s1, o);
    s2 += __shfl_xor(s2, o); s3 += __shfl_xor(s3, o);
  }
  if ((lane & 15) == 0) {
    int rq = r0 + (lane >> 4) * 4;
    atomicAdd(&s_row[rq + 0], s0);
    atomicAdd(&s_row[rq + 1], s1);
    atomicAdd(&s_row[rq + 2], s2);
    atomicAdd(&s_row[rq + 3], s3);
  }
}

// ---------------- final combine (single block) — OUTPUT IS FLOAT32 ----------------
__global__ void k_final(const float* __restrict__ m_u, const float* __restrict__ s_u,
                        const float* __restrict__ dis_u, const float* __restrict__ col_u,
                        const float* __restrict__ posd_u, const float* __restrict__ cross_u,
                        const float* __restrict__ m_p, const float* __restrict__ s_p,
                        const float* __restrict__ dis_p, const float* __restrict__ col_p,
                        const float* __restrict__ posd_p, const float* __restrict__ cross_p,
                        const float* __restrict__ pos_sc, const float* __restrict__ neg_sc,
                        const float* __restrict__ nms, const int* __restrict__ inv,
                        const float* __restrict__ S, float* __restrict__ out) {
  __shared__ float red[6][256];
  int t = threadIdx.x;
  float lpu = 0.f, lnu = 0.f, lpp = 0.f, lnp = 0.f, bp = 0.f, bn = 0.f;
  for (int r = t; r < BATCH; r += 256) {
    int ir = inv[r];
    {
      float M = m_u[r], Sv = s_u[r];
      float d2 = col_u[r];
      float d1 = dis_u[r];
      float nm2 = fmaxf(M, fmaxf(d1, d2));
      float ss = Sv * __expf(M - nm2) + __expf(d1 - nm2) + __expf(d2 - nm2);
      lpu += nm2 + logf(ss) - posd_u[r];
      float d1n = dis_u[ir];
      nm2 = fmaxf(M, fmaxf(d1n, d2));
      ss = Sv * __expf(M - nm2) + __expf(d1n - nm2) + __expf(d2 - nm2);
      lnu += nm2 + logf(ss) - cross_u[r];
    }
    {
      float M = m_p[r], Sv = s_p[r];
      float d2 = col_p[r];
      float d1 = dis_p[r];
      float nm2 = fmaxf(M, fmaxf(d1, d2));
      float ss = Sv * __expf(M - nm2) + __expf(d1 - nm2) + __expf(d2 - nm2);
      lpp += nm2 + logf(ss) - posd_p[r];
      float d1n = dis_p[ir];
      nm2 = fmaxf(M, fmaxf(d1n, d2));
      ss = Sv * __expf(M - nm2) + __expf(d1n - nm2) + __expf(d2 - nm2);
      lnp += nm2 + logf(ss) - cross_p[r];
    }
    float ps = pos_sc[r];
    bp += softplusf(neg_sc[r] - ps);
    bn += softplusf(nms[r] - ps);
  }
  red[0][t] = lpu; red[1][t] = lnu; red[2][t] = lpp;
  red[3][t] = lnp; red[4][t] = bp;  red[5][t] = bn;
  __syncthreads();
  for (int off = 128; off > 0; off >>= 1) {
    if (t < off)
      for (int c = 0; c < 6; c++) red[c][t] += red[c][t + off];
    __syncthreads();
  }
  if (t == 0) {
    const float inv_b = 1.f / (float)BATCH;
    float mbu = S[1] * inv_b;            // mean(beta_u)
    float b   = S[2] * inv_b;            // mean(beta_i)
    float cl_u = mbu * (red[0][0] * inv_b) + (1.f - mbu) * (red[1][0] * inv_b);
    float cl_p = b   * (red[2][0] * inv_b) + (1.f - b)   * (red[3][0] * inv_b);
    float main_m = b * (red[4][0] * inv_b) + (1.f - b) * (red[5][0] * inv_b);
    float reg = REGC * S[0] * inv_b;
    float loss = main_m + LAMBDA * (cl_u + cl_p) + reg;
    out[0] = loss;                       // float32
  }
}

extern "C" void kernel_launch(void* const* d_in, const int* in_sizes, int n_in,
                              void* d_out, int out_size, void* d_ws, size_t ws_size,
                              hipStream_t stream) {
  const float* uemb   = (const float*)d_in[0];
  const float* iemb   = (const float*)d_in[1];
  const int*   rows   = (const int*)d_in[2];
  const int*   cols   = (const int*)d_in[3];
  const int*   user   = (const int*)d_in[5];
  const int*   pos    = (const int*)d_in[6];
  const int*   neg    = (const int*)d_in[7];
  const float* beta_u = (const float*)d_in[8];
  const float* beta_i = (const float*)d_in[9];
  const int*   perm   = (const int*)d_in[10];
  const float* cu     = (const float*)d_in[11];
  const float* cp     = (const float*)d_in[12];

  char* w = (char*)d_ws;
  size_t off = 0;
  auto alloc = [&](size_t bytes) -> char* {
    char* p = w + off;
    off += (bytes + 255) & ~(size_t)255;
    return p;
  };
  unsigned short* x0h = (unsigned short*)alloc((size_t)ND * 2);
  unsigned short* x1h = (unsigned short*)alloc((size_t)ND * 2);
  unsigned short* x2h = (unsigned short*)alloc((size_t)ND * 2);
  unsigned short* x3h = (unsigned short*)alloc((size_t)ND * 2);
  int*   ev      = (int*)  alloc((size_t)NNZ * 4);
  int*   row_ptr = (int*)  alloc((size_t)(NN + 1) * 4);
  float* rsq     = (float*)alloc((size_t)NN * 4);
  float* sqd     = (float*)alloc((size_t)NN * 4);
  int*   bhist   = (int*)  alloc((size_t)NB * 4);
  int*   bbase   = (int*)  alloc((size_t)(NB + 1) * 4);
  int*   bcur    = (int*)  alloc((size_t)NB * 4);
  float* partR   = (float*)alloc((size_t)NGB * 4);
  float* ue      = (float*)alloc((size_t)BATCH * DIM * 4);
  float* pe      = (float*)alloc((size_t)BATCH * DIM * 4);
  float* ne      = (float*)alloc((size_t)BATCH * DIM * 4);
  float* An_u    = (float*)alloc((size_t)BATCH * DIM * 4);
  float* Pn_u    = (float*)alloc((size_t)BATCH * DIM * 4);
  float* An_p    = (float*)alloc((size_t)BATCH * DIM * 4);
  float* Pn_p    = (float*)alloc((size_t)BATCH * DIM * 4);
  unsigned short* An_uh = (unsigned short*)alloc((size_t)BATCH * DIM * 2);
  unsigned short* Pn_uh = (unsigned short*)alloc((size_t)BATCH * DIM * 2);
  unsigned short* An_ph = (unsigned short*)alloc((size_t)BATCH * DIM * 2);
  unsigned short* Pn_ph = (unsigned short*)alloc((size_t)BATCH * DIM * 2);
  float* pos_sc  = (float*)alloc((size_t)BATCH * 4);
  float* neg_sc  = (float*)alloc((size_t)BATCH * 4);
  float* nms     = (float*)alloc((size_t)BATCH * 4);
  float* dis_u   = (float*)alloc((size_t)BATCH * 4);
  float* col_u   = (float*)alloc((size_t)BATCH * 4);
  float* posd_u  = (float*)alloc((size_t)BATCH * 4);
  float* cross_u = (float*)alloc((size_t)BATCH * 4);
  float* m_u     = (float*)alloc((size_t)BATCH * 4);
  float* s_u     = (float*)alloc((size_t)BATCH * 4);
  float* dis_p   = (float*)alloc((size_t)BATCH * 4);
  float* col_p   = (float*)alloc((size_t)BATCH * 4);
  float* posd_p  = (float*)alloc((size_t)BATCH * 4);
  float* cross_p = (float*)alloc((size_t)BATCH * 4);
  float* m_p     = (float*)alloc((size_t)BATCH * 4);
  float* s_p     = (float*)alloc((size_t)BATCH * 4);
  int*   invp    = (int*)  alloc((size_t)BATCH * 4);
  float* c_u     = (float*)alloc(256);
  float* c_p     = (float*)alloc(256);
  float* S       = (float*)alloc(1024);

  // tmp (int per edge, 12.8MB) aliases x0h (19.2MB) — dead until k_inith,
  // which runs AFTER the CSR build.
  int* tmp = (int*)x0h;

  // 1. zero bucket hist + preset LSE state + invperm
  k_zero<<<(NN + 255) / 256, 256, 0, stream>>>(bhist, S, m_u, s_u, m_p, s_p, perm, invp);
  // 2. CSR build: bucket hist -> scan -> 2-pass bucket sort (row_ptr + deg tables in pass B)
  k_bhist<<<BHB, 256, 0, stream>>>(rows, bhist);
  k_bscan<<<1, 512, 0, stream>>>(bhist, bbase, bcur, row_ptr);
  k_bucketA<<<(NNZ + ACHUNK - 1) / ACHUNK, 256, 0, stream>>>(rows, cols, bcur, tmp);
  k_bucketB<<<NB, 512, 0, stream>>>(bbase, tmp, ev, row_ptr, rsq, sqd);
  // 3. init w0 = rsqrt(deg) * x0 (fp16)
  k_inith<<<(ND / 4 + 255) / 256, 256, 0, stream>>>((const float4*)uemb, (const float4*)iemb,
                                                    rsq, (uint2*)x0h);
  // 4. three GCN layers in w-space (wave-parallel ev + shuffle distribution)
  k_spmv<<<SPMVB, 256, 0, stream>>>(row_ptr, ev, x0h, x1h);
  k_spmv<<<SPMVB, 256, 0, stream>>>(row_ptr, ev, x1h, x2h);
  k_spmv<<<SPMVB, 256, 0, stream>>>(row_ptr, ev, x2h, x3h);
  // 5. batch gather (x = x0 + sqrt(deg)*(w1+w2+w3), batch rows only)
  k_gather<<<NGB, 256, 0, stream>>>((const float4*)uemb, (const float4*)iemb,
                                    (const uint2*)x1h, (const uint2*)x2h,
                                    (const uint2*)x3h, sqd, user, pos, neg,
                                    (float4*)ue, (float4*)pe, (float4*)ne, partR);
  // 6. mixes, scores, normalization (+ bf16 copies for MFMA)
  k_mixnorm<<<(BATCH * DIM) / 256, 256, 0, stream>>>(ue, pe, ne, beta_u, beta_i, perm,
                                                     An_u, Pn_u, An_p, Pn_p,
                                                     An_uh, Pn_uh, An_ph, Pn_ph,
                                                     pos_sc, neg_sc, nms);
  k_colpart<<<BATCH / 64, 256, 0, stream>>>(ue, pe, cu, cp, S);
  k_colnorm<<<1, 256, 0, stream>>>(beta_u, beta_i, partR, S, c_u, c_p);
  k_sims<<<(BATCH * DIM) / 256, 256, 0, stream>>>(An_u, Pn_u, An_p, Pn_p, c_u, c_p,
                                                  perm, invp,
                                                  dis_u, col_u, posd_u, cross_u,
                                                  dis_p, col_p, posd_p, cross_p);
  // 7. MFMA matmul + fixed-shift sumexp (user side, pos side)
  k_lse_mfma<<<512, 256, 0, stream>>>(An_uh, Pn_uh, s_u);
  k_lse_mfma<<<512, 256, 0, stream>>>(An_ph, Pn_ph, s_p);
  // 8. final combine
  k_final<<<1, 256, 0, stream>>>(m_u, s_u, dis_u, col_u, posd_u, cross_u,
                                 m_p, s_p, dis_p, col_p, posd_p, cross_p,
                                 pos_sc, neg_sc, nms, invp, S,
                                 (float*)d_out);
}

// Round 14
// 309.866 us; speedup vs baseline: 1.1251x; 1.0279x over previous
//
#include <hip/hip_runtime.h>
#include <hip/hip_bf16.h>
#include <hip/hip_fp16.h>

#define NUSERS 100000
#define NITEMS 50000
#define NN     150001          // total nodes
#define NNZ    3200000         // 2 * NNZ_INTER
#define BATCH  4096
#define DIM    64
#define ND     (NN * DIM)
#define ALPHA  0.25f           // 1/(N_LAYERS+1)
#define INVT   5.0f            // 1/TEMP
#define LAMBDA 0.1f
#define REGC   1.0e-4f
#define BKSH   9               // 512 nodes per bucket
#define NB     293             // ceil(150001/512)
#define ACHUNK 4096            // edges per bucketA block
#define M0     5.0f            // fixed LSE shift: logits = sim/T ∈ [-5,5]
#define NGB    256             // k_gather blocks (BATCH*16/256)
#define BHB    256             // k_bhist blocks
#define CMASK  0x3FFFF         // 18-bit col mask
#define SPMVB  2048            // k_spmv grid (8 blocks/CU -> 32 waves/CU)
#define W8SCALE 1024.f         // fp8 storage scale for w0
#define LGAIN   4.f            // per-layer gain (keeps fp8 values in sweet range)

typedef __attribute__((ext_vector_type(8))) short v8s;    // 8 bf16 (4 VGPRs)
typedef __attribute__((ext_vector_type(4))) float f32x4;  // MFMA acc
typedef __attribute__((ext_vector_type(2))) float f32x2;  // packed f32 pair

__device__ __forceinline__ float wred64(float v) {
  for (int o = 32; o > 0; o >>= 1) v += __shfl_xor(v, o);
  return v;
}

__device__ __forceinline__ float softplusf(float x) {
  return (x > 20.f) ? x : log1pf(__expf(x));
}

__device__ __forceinline__ unsigned short bf16r(float v) {
  unsigned x = __float_as_uint(v);
  return (unsigned short)((x + 0x7fff + ((x >> 16) & 1)) >> 16);   // RNE
}

// fp8 quad (uint = 4 x e4m3) -> float4 (HW cvt)
__device__ __forceinline__ float4 q8f(unsigned W) {
  f32x2 lo = __builtin_amdgcn_cvt_pk_f32_fp8(W, false);
  f32x2 hi = __builtin_amdgcn_cvt_pk_f32_fp8(W, true);
  return make_float4(lo.x, lo.y, hi.x, hi.y);
}

// float4 -> fp8 quad
__device__ __forceinline__ unsigned f4q8(float a, float b, float c, float d) {
  int w = __builtin_amdgcn_cvt_pk_fp8_f32(a, b, 0, false);
  w = __builtin_amdgcn_cvt_pk_fp8_f32(c, d, w, true);
  return (unsigned)w;
}

// ---------------- zero scratch + preset LSE state + invperm ----------------
__global__ void k_zero(int* __restrict__ bhist, float* __restrict__ S,
                       float* __restrict__ m_u, float* __restrict__ s_u,
                       float* __restrict__ m_p, float* __restrict__ s_p,
                       const int* __restrict__ perm, int* __restrict__ inv) {
  int i = blockIdx.x * blockDim.x + threadIdx.x;
  if (i < NB) bhist[i] = 0;
  if (i < 256) S[i] = 0.f;
  if (i < BATCH) {
    s_u[i] = 0.f; s_p[i] = 0.f; m_u[i] = M0; m_p[i] = M0;
    inv[perm[i]] = i;
  }
}

// ---------------- s0 = W8SCALE * rsqrt(deg) * x0, fp8 quads ----------------
__global__ void k_inith(const float4* __restrict__ uemb, const float4* __restrict__ iemb,
                        const float* __restrict__ rsq, unsigned* __restrict__ x0q) {
  int q = blockIdx.x * blockDim.x + threadIdx.x;   // quads: NN*16
  if (q >= NN * 16) return;
  int n = q >> 4;                                   // 16 quads per node
  float4 v = (n < NUSERS) ? uemb[q] : iemb[q - NUSERS * 16];
  float r = rsq[n] * W8SCALE;
  x0q[q] = f4q8(v.x * r, v.y * r, v.z * r, v.w * r);
}

// ---------------- bucket histogram: LDS-private, 293 global atomics per block -----------
__global__ __launch_bounds__(256) void k_bhist(const int* __restrict__ rows,
                                               int* __restrict__ bhist) {
  __shared__ int lh[NB];
  int t = threadIdx.x;
  for (int i = t; i < NB; i += 256) lh[i] = 0;
  __syncthreads();
  const int per = (NNZ + BHB - 1) / BHB;
  int base = blockIdx.x * per;
  int end = min(base + per, NNZ);
  for (int e = base + t; e < end; e += 256)
    atomicAdd(&lh[rows[e] >> BKSH], 1);
  __syncthreads();
  for (int i = t; i < NB; i += 256) {
    int c = lh[i];
    if (c) atomicAdd(&bhist[i], c);
  }
}

// ---------------- bucket scan (one block, 512 threads) ----------------
__global__ __launch_bounds__(512) void k_bscan(const int* __restrict__ bhist,
                                               int* __restrict__ bbase, int* __restrict__ bcur,
                                               int* __restrict__ row_ptr) {
  __shared__ int sc[512];
  int t = threadIdx.x;
  int v = (t < NB) ? bhist[t] : 0;
  sc[t] = v;
  __syncthreads();
  for (int off = 1; off < 512; off <<= 1) {
    int u = (t >= off) ? sc[t - off] : 0;
    __syncthreads();
    sc[t] += u;
    __syncthreads();
  }
  int ex = sc[t] - v;                  // exclusive prefix
  if (t < NB) { bbase[t] = ex; bcur[t] = ex; }
  if (t == NB - 1) { bbase[NB] = ex + v; row_ptr[NN] = ex + v; }  // == NNZ
}

// ---------------- bucket pass A: LDS counting-sort, packed 4-byte output ----------------
// packed word: col | (row&511)<<18   (col < 2^18, row-local < 2^9)
__global__ __launch_bounds__(256) void k_bucketA(const int* __restrict__ rows,
                                                 const int* __restrict__ cols,
                                                 int* __restrict__ bcur,
                                                 int* __restrict__ tmp) {
  __shared__ int lhist[NB];
  __shared__ int lscan[NB];
  __shared__ int ldelta[NB];
  __shared__ int lcnt[NB];
  __shared__ int2 ent[ACHUNK];        // x=packed col/rowlocal, y=ldelta
  int t = threadIdx.x;
  int base = blockIdx.x * ACHUNK;
  for (int b = t; b < NB; b += 256) { lhist[b] = 0; lcnt[b] = 0; }
  __syncthreads();
  int pkv[16], bkt[16];
  int nval = 0;
#pragma unroll
  for (int k = 0; k < 16; k++) {
    int e = base + t + k * 256;                 // coalesced
    if (e < NNZ) {
      int r = rows[e];
      pkv[k] = cols[e] | ((r & 511) << 18);
      bkt[k] = r >> BKSH;
      atomicAdd(&lhist[bkt[k]], 1);
      nval = k + 1;
    }
  }
  __syncthreads();
  if (t == 0) {
    int run = 0;
    for (int b = 0; b < NB; b++) { lscan[b] = run; run += lhist[b]; }
  }
  __syncthreads();
  for (int b = t; b < NB; b += 256) {
    int c = lhist[b];
    int g = (c > 0) ? atomicAdd(&bcur[b], c) : 0;
    ldelta[b] = g - lscan[b];
  }
  __syncthreads();
#pragma unroll
  for (int k = 0; k < 16; k++) {
    if (k < nval) {
      int b = bkt[k];
      int lp = atomicAdd(&lcnt[b], 1);
      ent[lscan[b] + lp] = make_int2(pkv[k], ldelta[b]);
    }
  }
  __syncthreads();
  int tot = min(ACHUNK, NNZ - base);
  for (int j = t; j < tot; j += 256) {
    int2 E = ent[j];
    tmp[E.y + j] = E.x;                        // contiguous run per bucket -> full lines
  }
}

// ---------------- bucket pass B: row_ptr + deg tables + final scatter ----------------
__global__ __launch_bounds__(512) void k_bucketB(const int* __restrict__ bbase,
                                                 const int* __restrict__ tmp,
                                                 int* __restrict__ ev,
                                                 int* __restrict__ row_ptr,
                                                 float* __restrict__ rsq,
                                                 float* __restrict__ sqd) {
  __shared__ int h[512], sc[512], c2[512], rstart[512];
  int b = blockIdx.x, t = threadIdx.x;
  int nbase = b << BKSH;
  h[t] = 0; c2[t] = 0;
  __syncthreads();
  int beg = bbase[b], end = bbase[b + 1];
  for (int j = beg + t; j < end; j += 512)
    atomicAdd(&h[tmp[j] >> 18], 1);
  __syncthreads();
  int v = h[t];
  sc[t] = v;
  __syncthreads();
  for (int off = 1; off < 512; off <<= 1) {
    int u = (t >= off) ? sc[t - off] : 0;
    __syncthreads();
    sc[t] += u;
    __syncthreads();
  }
  int rp = beg + sc[t] - v;            // exclusive scan -> row start
  rstart[t] = rp;
  int node = nbase + t;
  if (node < NN) {
    row_ptr[node] = rp;
    float fd = (float)v;
    rsq[node] = (v > 0) ? rsqrtf(fd) : 0.f;
    sqd[node] = sqrtf(fd);
  }
  __syncthreads();
  for (int j = beg + t; j < end; j += 512) {
    int w = tmp[j];
    int ln = w >> 18;
    int lp = atomicAdd(&c2[ln], 1);
    ev[rstart[ln] + lp] = w & CMASK;
  }
}

// ---------------- gather SpMV: fp8 table (1 line/edge) + wave-parallel ev + shuffle ------
// s_out = (LGAIN/deg) * sum_neighbors(s_in). fp32 packed accumulate.
__global__ __launch_bounds__(256) void k_spmv(const int* __restrict__ row_ptr,
                                              const int* __restrict__ ev,
                                              const unsigned* __restrict__ cur,
                                              unsigned* __restrict__ nxt) {
  int lane = threadIdx.x & 63;
  int g = lane >> 4;                 // gather group 0..3
  int q4 = lane & 15;                // word (4 dims) within row; row = 64B = 1 line
  for (int node0 = blockIdx.x * 4 + (threadIdx.x >> 6); node0 < NN;
       node0 += SPMVB * 4) {
    int node = __builtin_amdgcn_readfirstlane(node0);
    int beg = row_ptr[node], end = row_ptr[node + 1];
    int deg = end - beg;
    f32x2 a0 = {0.f, 0.f}, a1 = {0.f, 0.f};
    for (int base = 0; base < deg; base += 64) {
      int idx = base + lane;
      int col = 0;
      if (idx < deg) col = ev[beg + idx];        // ONE VMEM per 64 edges
      int cnt = min(deg - base, 64);
      int nit = (cnt + 15) >> 4;                 // 16 edges per iteration
      for (int it = 0; it < nit; ++it) {
        int e0 = it * 16 + g;                    // group g's 4 edges this iter
        int e1 = e0 + 4, e2 = e0 + 8, e3 = e0 + 12;
        int c0 = __shfl(col, e0);
        int c1 = __shfl(col, e1);
        int c2 = __shfl(col, e2);
        int c3 = __shfl(col, e3);
        unsigned W0 = 0u, W1 = 0u, W2 = 0u, W3 = 0u;
        if (e0 < cnt) W0 = cur[c0 * 16 + q4];    // 16 lanes x 4B = 64B = 1 line
        if (e1 < cnt) W1 = cur[c1 * 16 + q4];
        if (e2 < cnt) W2 = cur[c2 * 16 + q4];
        if (e3 < cnt) W3 = cur[c3 * 16 + q4];
        a0 += __builtin_amdgcn_cvt_pk_f32_fp8(W0, false);
        a1 += __builtin_amdgcn_cvt_pk_f32_fp8(W0, true);
        a0 += __builtin_amdgcn_cvt_pk_f32_fp8(W1, false);
        a1 += __builtin_amdgcn_cvt_pk_f32_fp8(W1, true);
        a0 += __builtin_amdgcn_cvt_pk_f32_fp8(W2, false);
        a1 += __builtin_amdgcn_cvt_pk_f32_fp8(W2, true);
        a0 += __builtin_amdgcn_cvt_pk_f32_fp8(W3, false);
        a1 += __builtin_amdgcn_cvt_pk_f32_fp8(W3, true);
      }
    }
    // reduce across the 4 gather groups
    a0.x += __shfl_xor(a0.x, 16); a0.y += __shfl_xor(a0.y, 16);
    a1.x += __shfl_xor(a1.x, 16); a1.y += __shfl_xor(a1.y, 16);
    a0.x += __shfl_xor(a0.x, 32); a0.y += __shfl_xor(a0.y, 32);
    a1.x += __shfl_xor(a1.x, 32); a1.y += __shfl_xor(a1.y, 32);
    if (g == 0) {
      float sc = (deg > 0) ? LGAIN / (float)deg : 0.f;
      unsigned w = f4q8(a0.x * sc, a0.y * sc, a1.x * sc, a1.y * sc);
      __builtin_nontemporal_store(w, &nxt[node * 16 + q4]);
    }
  }
}

// ---------------- batch gather: ue = ALPHA*(x0 + sqd*(s1/4096 + s2/16384 + s3/65536)) ----
__global__ __launch_bounds__(256) void k_gather(const float4* __restrict__ uemb4,
                                                const float4* __restrict__ iemb4,
                                                const unsigned* __restrict__ x1q,
                                                const unsigned* __restrict__ x2q,
                                                const unsigned* __restrict__ x3q,
                                                const float* __restrict__ sqd,
                                                const int* __restrict__ user,
                                                const int* __restrict__ pos,
                                                const int* __restrict__ neg,
                                                float4* __restrict__ ue4,
                                                float4* __restrict__ pe4,
                                                float4* __restrict__ ne4,
                                                float* __restrict__ partR) {
  __shared__ float sred[256];
  const float G1 = 1.f / (W8SCALE * LGAIN);            // 1/4096
  const float G2 = 0.25f, G3 = 0.0625f;                // relative layer gains
  int t = threadIdx.x;
  int gid = blockIdx.x * 256 + t;    // BATCH*16 exact
  int i = gid >> 4, q = gid & 15;
  int u = user[i], p = pos[i], n = neg[i];
  int nu = u, np = NUSERS + p, nn = NUSERS + n;
  int qu = nu * 16 + q, qp = np * 16 + q, qn = nn * 16 + q;
  float4 eu = uemb4[qu];                       // x0 user (also reg term)
  float4 ep = iemb4[p * 16 + q];               // x0 pos  (also reg term)
  float4 en = iemb4[n * 16 + q];               // x0 neg  (also reg term)
  float ku = sqd[nu] * G1, kp = sqd[np] * G1, kn = sqd[nn] * G1;
  float4 a1 = q8f(x1q[qu]), a2 = q8f(x2q[qu]), a3 = q8f(x3q[qu]);
  float4 b1 = q8f(x1q[qp]), b2 = q8f(x2q[qp]), b3 = q8f(x3q[qp]);
  float4 c1 = q8f(x1q[qn]), c2 = q8f(x2q[qn]), c3 = q8f(x3q[qn]);
  float4 su = make_float4(ALPHA * (eu.x + ku * (a1.x + G2 * a2.x + G3 * a3.x)),
                          ALPHA * (eu.y + ku * (a1.y + G2 * a2.y + G3 * a3.y)),
                          ALPHA * (eu.z + ku * (a1.z + G2 * a2.z + G3 * a3.z)),
                          ALPHA * (eu.w + ku * (a1.w + G2 * a2.w + G3 * a3.w)));
  float4 sp = make_float4(ALPHA * (ep.x + kp * (b1.x + G2 * b2.x + G3 * b3.x)),
                          ALPHA * (ep.y + kp * (b1.y + G2 * b2.y + G3 * b3.y)),
                          ALPHA * (ep.z + kp * (b1.z + G2 * b2.z + G3 * b3.z)),
                          ALPHA * (ep.w + kp * (b1.w + G2 * b2.w + G3 * b3.w)));
  float4 sn = make_float4(ALPHA * (en.x + kn * (c1.x + G2 * c2.x + G3 * c3.x)),
                          ALPHA * (en.y + kn * (c1.y + G2 * c2.y + G3 * c3.y)),
                          ALPHA * (en.z + kn * (c1.z + G2 * c2.z + G3 * c3.z)),
                          ALPHA * (en.w + kn * (c1.w + G2 * c2.w + G3 * c3.w)));
  ue4[gid] = su;  pe4[gid] = sp;  ne4[gid] = sn;
  sred[t] = eu.x * eu.x + eu.y * eu.y + eu.z * eu.z + eu.w * eu.w
          + ep.x * ep.x + ep.y * ep.y + ep.z * ep.z + ep.w * ep.w
          + en.x * en.x + en.y * en.y + en.z * en.z + en.w * en.w;
  __syncthreads();
  for (int off = 128; off > 0; off >>= 1) {
    if (t < off) sred[t] += sred[t + off];
    __syncthreads();
  }
  if (t == 0) partR[blockIdx.x] = sred[0];
}

// ---------------- mixes, scores, row normalization (wave per row); also emit bf16 ----------
__global__ void k_mixnorm(const float* __restrict__ ue, const float* __restrict__ pe,
                          const float* __restrict__ ne, const float* __restrict__ beta_u,
                          const float* __restrict__ beta_i, const int* __restrict__ perm,
                          float* __restrict__ An_u, float* __restrict__ Pn_u,
                          float* __restrict__ An_p, float* __restrict__ Pn_p,
                          unsigned short* __restrict__ An_uh, unsigned short* __restrict__ Pn_uh,
                          unsigned short* __restrict__ An_ph, unsigned short* __restrict__ Pn_ph,
                          float* __restrict__ pos_sc, float* __restrict__ neg_sc,
                          float* __restrict__ nms) {
  int gid = blockIdx.x * blockDim.x + threadIdx.x;   // BATCH*64 exact
  int i = gid >> 6, d = gid & 63;
  int pi = perm[i];
  float uei = ue[i * DIM + d], pei = pe[i * DIM + d], nei = ne[i * DIM + d];
  float ud = ue[pi * DIM + d], pd = pe[pi * DIM + d], nd = ne[pi * DIM + d];
  float bu = beta_u[i], bi = beta_i[i];
  float um = bu * uei + (1.f - bu) * ud;
  float pm = bi * pei + (1.f - bi) * pd;
  float nm = bi * nei + (1.f - bi) * nd;
  float r0 = uei * pei, r1 = uei * nei, r2 = uei * nm;
  float r3 = uei * uei, r4 = um * um, r5 = pei * pei, r6 = pm * pm;
  for (int o = 32; o > 0; o >>= 1) {
    r0 += __shfl_xor(r0, o); r1 += __shfl_xor(r1, o); r2 += __shfl_xor(r2, o);
    r3 += __shfl_xor(r3, o); r4 += __shfl_xor(r4, o); r5 += __shfl_xor(r5, o);
    r6 += __shfl_xor(r6, o);
  }
  if (d == 0) { pos_sc[i] = r0; neg_sc[i] = r1; nms[i] = r2; }
  float inu  = 1.f / fmaxf(sqrtf(r3), 1e-12f);
  float inum = 1.f / fmaxf(sqrtf(r4), 1e-12f);
  float inp  = 1.f / fmaxf(sqrtf(r5), 1e-12f);
  float inpm = 1.f / fmaxf(sqrtf(r6), 1e-12f);
  float a0 = uei * inu, p0 = um * inum, a1 = pei * inp, p1 = pm * inpm;
  An_u[gid] = a0;  Pn_u[gid] = p0;  An_p[gid] = a1;  Pn_p[gid] = p1;
  An_uh[gid] = bf16r(a0); Pn_uh[gid] = bf16r(p0);
  An_ph[gid] = bf16r(a1); Pn_ph[gid] = bf16r(p1);
}

// ---------------- collective-mix: parallel partial sums (64 blocks) ----------------
__global__ void k_colpart(const float* __restrict__ ue, const float* __restrict__ pe,
                          const float* __restrict__ cu, const float* __restrict__ cp,
                          float* __restrict__ S) {
  __shared__ float smu[4][64], smp[4][64];
  int t = threadIdx.x, d = t & 63, q = t >> 6;
  int r0 = blockIdx.x * 64 + q * 16;
  float su = 0.f, sp = 0.f;
#pragma unroll 4
  for (int i = r0; i < r0 + 16; ++i) {
    su = fmaf(cu[i], ue[i * DIM + d], su);
    sp = fmaf(cp[i], pe[i * DIM + d], sp);
  }
  smu[q][d] = su; smp[q][d] = sp;
  __syncthreads();
  if (t < 64) {
    atomicAdd(&S[64 + d],  smu[0][d] + smu[1][d] + smu[2][d] + smu[3][d]);
    atomicAdd(&S[128 + d], smp[0][d] + smp[1][d] + smp[2][d] + smp[3][d]);
  }
}

// ---------------- colnorm + small sums (one block, 256 threads) ----------------
__global__ void k_colnorm(const float* __restrict__ beta_u, const float* __restrict__ beta_i,
                          const float* __restrict__ partR, float* __restrict__ S,
                          float* __restrict__ c_u, float* __restrict__ c_p) {
  __shared__ float a[256], b[256], c[256];
  int t = threadIdx.x;
  float su = 0.f, si = 0.f, sr = 0.f;
  for (int j = t; j < BATCH; j += 256) { su += beta_u[j]; si += beta_i[j]; }
  for (int j = t; j < NGB; j += 256) sr += partR[j];
  a[t] = su; b[t] = si; c[t] = sr;
  __syncthreads();
  for (int off = 128; off > 0; off >>= 1) {
    if (t < off) { a[t] += a[t + off]; b[t] += b[t + off]; c[t] += c[t + off]; }
    __syncthreads();
  }
  if (t == 0) { S[0] = c[0]; S[1] = a[0]; S[2] = b[0]; }
  // colnorm: waves 0,1 (uniform branch per wave)
  if (t < 128) {
    int d = t & 63;
    float v = (t < 64) ? S[64 + d] : S[128 + d];
    float n = wred64(v * v);
    float inv = 1.f / fmaxf(sqrtf(n), 1e-12f);
    if (t < 64) c_u[d] = v * inv;
    else        c_p[d] = v * inv;
  }
}

// ---------------- per-row sims (wave per row) ----------------
__global__ void k_sims(const float* __restrict__ An_u, const float* __restrict__ Pn_u,
                       const float* __restrict__ An_p, const float* __restrict__ Pn_p,
                       const float* __restrict__ c_u, const float* __restrict__ c_p,
                       const int* __restrict__ perm, const int* __restrict__ inv,
                       float* __restrict__ dis_u, float* __restrict__ col_u,
                       float* __restrict__ posd_u, float* __restrict__ cross_u,
                       float* __restrict__ dis_p, float* __restrict__ col_p,
                       float* __restrict__ posd_p, float* __restrict__ cross_p) {
  int gid = blockIdx.x * blockDim.x + threadIdx.x;
  int r = gid >> 6, d = gid & 63;
  int pr = perm[r], ir = inv[r];
  float au = An_u[r * DIM + d], pu = Pn_u[r * DIM + d];
  float ap = An_p[r * DIM + d], pp = Pn_p[r * DIM + d];
  float r0 = au * An_u[pr * DIM + d];
  float r1 = au * c_u[d];
  float r2 = au * pu;
  float r3 = au * Pn_u[ir * DIM + d];
  float r4 = ap * An_p[pr * DIM + d];
  float r5 = ap * c_p[d];
  float r6 = ap * pp;
  float r7 = ap * Pn_p[ir * DIM + d];
  for (int o = 32; o > 0; o >>= 1) {
    r0 += __shfl_xor(r0, o); r1 += __shfl_xor(r1, o); r2 += __shfl_xor(r2, o);
    r3 += __shfl_xor(r3, o); r4 += __shfl_xor(r4, o); r5 += __shfl_xor(r5, o);
    r6 += __shfl_xor(r6, o); r7 += __shfl_xor(r7, o);
  }
  if (d == 0) {
    dis_u[r] = r0 * INVT; col_u[r] = r1 * INVT; posd_u[r] = r2 * INVT; cross_u[r] = r3 * INVT;
    dis_p[r] = r4 * INVT; col_p[r] = r5 * INVT; posd_p[r] = r6 * INVT; cross_p[r] = r7 * INVT;
  }
}

// ---------------- MFMA fused matmul + fixed-shift sumexp over G = An @ Pn^T / T ----------
__global__ __launch_bounds__(256) void k_lse_mfma(const unsigned short* __restrict__ Anh,
                                                  const unsigned short* __restrict__ Pnh,
                                                  float* __restrict__ s_row) {
  const float C1 = INVT * 1.4426950408889634f;   // INVT*log2(e)
  int rb = blockIdx.x >> 3, cb = blockIdx.x & 7;
  int w = threadIdx.x >> 6, lane = threadIdx.x & 63;
  int r0 = rb * 64 + w * 16;
  int arow = r0 + (lane & 15);
  int koff = (lane >> 4) * 8;
  v8s a_lo = *(const v8s*)&Anh[arow * DIM + koff];
  v8s a_hi = *(const v8s*)&Anh[arow * DIM + koff + 32];
  float s0 = 0.f, s1 = 0.f, s2 = 0.f, s3 = 0.f;
  int cbase = cb * 512;
#pragma unroll 2
  for (int c0 = cbase; c0 < cbase + 512; c0 += 16) {
    int brow = c0 + (lane & 15);
    v8s b_lo = *(const v8s*)&Pnh[brow * DIM + koff];
    v8s b_hi = *(const v8s*)&Pnh[brow * DIM + koff + 32];
    f32x4 acc = {0.f, 0.f, 0.f, 0.f};
    acc = __builtin_amdgcn_mfma_f32_16x16x32_bf16(a_lo, b_lo, acc, 0, 0, 0);
    acc = __builtin_amdgcn_mfma_f32_16x16x32_bf16(a_hi, b_hi, acc, 0, 0, 0);
    s0 += exp2f(fmaf(acc[0], C1, -C1));
    s1 += exp2f(fmaf(acc[1], C1, -C1));
    s2 += exp2f(fmaf(acc[2], C1, -C1));
    s3 += exp2f(fmaf(acc[3], C1, -C1));
  }
  // sum the 16 col-slots of each row (C/D: col=lane&15, row=(lane>>4)*4+reg)
  for (int o = 1; o <= 8; o <<= 1) {
    s0 += __shfl_xor(s0, o); s1 += __shfl_xor(s1, o);
    s2 += __shfl_xor(s2, o); s3 += __shfl_xor(s3, o);
  }
  if ((lane & 15) == 0) {
    int rq = r0 + (lane >> 4) * 4;
    atomicAdd(&s_row[rq + 0], s0);
    atomicAdd(&s_row[rq + 1], s1);
    atomicAdd(&s_row[rq + 2], s2);
    atomicAdd(&s_row[rq + 3], s3);
  }
}

// ---------------- final combine (single block) — OUTPUT IS FLOAT32 ----------------
__global__ void k_final(const float* __restrict__ m_u, const float* __restrict__ s_u,
                        const float* __restrict__ dis_u, const float* __restrict__ col_u,
                        const float* __restrict__ posd_u, const float* __restrict__ cross_u,
                        const float* __restrict__ m_p, const float* __restrict__ s_p,
                        const float* __restrict__ dis_p, const float* __restrict__ col_p,
                        const float* __restrict__ posd_p, const float* __restrict__ cross_p,
                        const float* __restrict__ pos_sc, const float* __restrict__ neg_sc,
                        const float* __restrict__ nms, const int* __restrict__ inv,
                        const float* __restrict__ S, float* __restrict__ out) {
  __shared__ float red[6][256];
  int t = threadIdx.x;
  float lpu = 0.f, lnu = 0.f, lpp = 0.f, lnp = 0.f, bp = 0.f, bn = 0.f;
  for (int r = t; r < BATCH; r += 256) {
    int ir = inv[r];
    {
      float M = m_u[r], Sv = s_u[r];
      float d2 = col_u[r];
      float d1 = dis_u[r];
      float nm2 = fmaxf(M, fmaxf(d1, d2));
      float ss = Sv * __expf(M - nm2) + __expf(d1 - nm2) + __expf(d2 - nm2);
      lpu += nm2 + logf(ss) - posd_u[r];
      float d1n = dis_u[ir];
      nm2 = fmaxf(M, fmaxf(d1n, d2));
      ss = Sv * __expf(M - nm2) + __expf(d1n - nm2) + __expf(d2 - nm2);
      lnu += nm2 + logf(ss) - cross_u[r];
    }
    {
      float M = m_p[r], Sv = s_p[r];
      float d2 = col_p[r];
      float d1 = dis_p[r];
      float nm2 = fmaxf(M, fmaxf(d1, d2));
      float ss = Sv * __expf(M - nm2) + __expf(d1 - nm2) + __expf(d2 - nm2);
      lpp += nm2 + logf(ss) - posd_p[r];
      float d1n = dis_p[ir];
      nm2 = fmaxf(M, fmaxf(d1n, d2));
      ss = Sv * __expf(M - nm2) + __expf(d1n - nm2) + __expf(d2 - nm2);
      lnp += nm2 + logf(ss) - cross_p[r];
    }
    float ps = pos_sc[r];
    bp += softplusf(neg_sc[r] - ps);
    bn += softplusf(nms[r] - ps);
  }
  red[0][t] = lpu; red[1][t] = lnu; red[2][t] = lpp;
  red[3][t] = lnp; red[4][t] = bp;  red[5][t] = bn;
  __syncthreads();
  for (int off = 128; off > 0; off >>= 1) {
    if (t < off)
      for (int c = 0; c < 6; c++) red[c][t] += red[c][t + off];
    __syncthreads();
  }
  if (t == 0) {
    const float inv_b = 1.f / (float)BATCH;
    float mbu = S[1] * inv_b;            // mean(beta_u)
    float b   = S[2] * inv_b;            // mean(beta_i)
    float cl_u = mbu * (red[0][0] * inv_b) + (1.f - mbu) * (red[1][0] * inv_b);
    float cl_p = b   * (red[2][0] * inv_b) + (1.f - b)   * (red[3][0] * inv_b);
    float main_m = b * (red[4][0] * inv_b) + (1.f - b) * (red[5][0] * inv_b);
    float reg = REGC * S[0] * inv_b;
    float loss = main_m + LAMBDA * (cl_u + cl_p) + reg;
    out[0] = loss;                       // float32
  }
}

extern "C" void kernel_launch(void* const* d_in, const int* in_sizes, int n_in,
                              void* d_out, int out_size, void* d_ws, size_t ws_size,
                              hipStream_t stream) {
  const float* uemb   = (const float*)d_in[0];
  const float* iemb   = (const float*)d_in[1];
  const int*   rows   = (const int*)d_in[2];
  const int*   cols   = (const int*)d_in[3];
  const int*   user   = (const int*)d_in[5];
  const int*   pos    = (const int*)d_in[6];
  const int*   neg    = (const int*)d_in[7];
  const float* beta_u = (const float*)d_in[8];
  const float* beta_i = (const float*)d_in[9];
  const int*   perm   = (const int*)d_in[10];
  const float* cu     = (const float*)d_in[11];
  const float* cp     = (const float*)d_in[12];

  char* w = (char*)d_ws;
  size_t off = 0;
  auto alloc = [&](size_t bytes) -> char* {
    char* p = w + off;
    off += (bytes + 255) & ~(size_t)255;
    return p;
  };
  unsigned* x0q = (unsigned*)alloc((size_t)NN * 16 * 4);   // fp8 quads: 9.6MB each
  unsigned* x1q = (unsigned*)alloc((size_t)NN * 16 * 4);
  unsigned* x2q = (unsigned*)alloc((size_t)NN * 16 * 4);
  unsigned* x3q = (unsigned*)alloc((size_t)NN * 16 * 4);
  int*   ev      = (int*)  alloc((size_t)NNZ * 4);
  int*   row_ptr = (int*)  alloc((size_t)(NN + 1) * 4);
  float* rsq     = (float*)alloc((size_t)NN * 4);
  float* sqd     = (float*)alloc((size_t)NN * 4);
  int*   bhist   = (int*)  alloc((size_t)NB * 4);
  int*   bbase   = (int*)  alloc((size_t)(NB + 1) * 4);
  int*   bcur    = (int*)  alloc((size_t)NB * 4);
  float* partR   = (float*)alloc((size_t)NGB * 4);
  float* ue      = (float*)alloc((size_t)BATCH * DIM * 4);
  float* pe      = (float*)alloc((size_t)BATCH * DIM * 4);
  float* ne      = (float*)alloc((size_t)BATCH * DIM * 4);
  float* An_u    = (float*)alloc((size_t)BATCH * DIM * 4);
  float* Pn_u    = (float*)alloc((size_t)BATCH * DIM * 4);
  float* An_p    = (float*)alloc((size_t)BATCH * DIM * 4);
  float* Pn_p    = (float*)alloc((size_t)BATCH * DIM * 4);
  unsigned short* An_uh = (unsigned short*)alloc((size_t)BATCH * DIM * 2);
  unsigned short* Pn_uh = (unsigned short*)alloc((size_t)BATCH * DIM * 2);
  unsigned short* An_ph = (unsigned short*)alloc((size_t)BATCH * DIM * 2);
  unsigned short* Pn_ph = (unsigned short*)alloc((size_t)BATCH * DIM * 2);
  float* pos_sc  = (float*)alloc((size_t)BATCH * 4);
  float* neg_sc  = (float*)alloc((size_t)BATCH * 4);
  float* nms     = (float*)alloc((size_t)BATCH * 4);
  float* dis_u   = (float*)alloc((size_t)BATCH * 4);
  float* col_u   = (float*)alloc((size_t)BATCH * 4);
  float* posd_u  = (float*)alloc((size_t)BATCH * 4);
  float* cross_u = (float*)alloc((size_t)BATCH * 4);
  float* m_u     = (float*)alloc((size_t)BATCH * 4);
  float* s_u     = (float*)alloc((size_t)BATCH * 4);
  float* dis_p   = (float*)alloc((size_t)BATCH * 4);
  float* col_p   = (float*)alloc((size_t)BATCH * 4);
  float* posd_p  = (float*)alloc((size_t)BATCH * 4);
  float* cross_p = (float*)alloc((size_t)BATCH * 4);
  float* m_p     = (float*)alloc((size_t)BATCH * 4);
  float* s_p     = (float*)alloc((size_t)BATCH * 4);
  int*   invp    = (int*)  alloc((size_t)BATCH * 4);
  float* c_u     = (float*)alloc(256);
  float* c_p     = (float*)alloc(256);
  float* S       = (float*)alloc(1024);

  // tmp (int per edge, 12.8MB) aliases x0q+x1q (19.2MB) — dead until k_inith,
  // which runs AFTER the CSR build.
  int* tmp = (int*)x0q;

  // 1. zero bucket hist + preset LSE state + invperm
  k_zero<<<(NN + 255) / 256, 256, 0, stream>>>(bhist, S, m_u, s_u, m_p, s_p, perm, invp);
  // 2. CSR build: bucket hist -> scan -> 2-pass bucket sort (row_ptr + deg tables in pass B)
  k_bhist<<<BHB, 256, 0, stream>>>(rows, bhist);
  k_bscan<<<1, 512, 0, stream>>>(bhist, bbase, bcur, row_ptr);
  k_bucketA<<<(NNZ + ACHUNK - 1) / ACHUNK, 256, 0, stream>>>(rows, cols, bcur, tmp);
  k_bucketB<<<NB, 512, 0, stream>>>(bbase, tmp, ev, row_ptr, rsq, sqd);
  // 3. init s0 = 1024 * rsqrt(deg) * x0 (fp8)
  k_inith<<<(NN * 16 + 255) / 256, 256, 0, stream>>>((const float4*)uemb, (const float4*)iemb,
                                                     rsq, x0q);
  // 4. three GCN layers (fp8 table = 1 line/edge, wave-parallel ev, fp32 accumulate)
  k_spmv<<<SPMVB, 256, 0, stream>>>(row_ptr, ev, x0q, x1q);
  k_spmv<<<SPMVB, 256, 0, stream>>>(row_ptr, ev, x1q, x2q);
  k_spmv<<<SPMVB, 256, 0, stream>>>(row_ptr, ev, x2q, x3q);
  // 5. batch gather (exact power-of-2 unscaling, batch rows only)
  k_gather<<<NGB, 256, 0, stream>>>((const float4*)uemb, (const float4*)iemb,
                                    x1q, x2q, x3q, sqd, user, pos, neg,
                                    (float4*)ue, (float4*)pe, (float4*)ne, partR);
  // 6. mixes, scores, normalization (+ bf16 copies for MFMA)
  k_mixnorm<<<(BATCH * DIM) / 256, 256, 0, stream>>>(ue, pe, ne, beta_u, beta_i, perm,
                                                     An_u, Pn_u, An_p, Pn_p,
                                                     An_uh, Pn_uh, An_ph, Pn_ph,
                                                     pos_sc, neg_sc, nms);
  k_colpart<<<BATCH / 64, 256, 0, stream>>>(ue, pe, cu, cp, S);
  k_colnorm<<<1, 256, 0, stream>>>(beta_u, beta_i, partR, S, c_u, c_p);
  k_sims<<<(BATCH * DIM) / 256, 256, 0, stream>>>(An_u, Pn_u, An_p, Pn_p, c_u, c_p,
                                                  perm, invp,
                                                  dis_u, col_u, posd_u, cross_u,
                                                  dis_p, col_p, posd_p, cross_p);
  // 7. MFMA matmul + fixed-shift sumexp (user side, pos side)
  k_lse_mfma<<<512, 256, 0, stream>>>(An_uh, Pn_uh, s_u);
  k_lse_mfma<<<512, 256, 0, stream>>>(An_ph, Pn_ph, s_p);
  // 8. final combine
  k_final<<<1, 256, 0, stream>>>(m_u, s_u, dis_u, col_u, posd_u, cross_u,
                                 m_p, s_p, dis_p, col_p, posd_p, cross_p,
                                 pos_sc, neg_sc, nms, invp, S,
                                 (float*)d_out);
}